// Round 15
// baseline (475.071 us; speedup 1.0000x reference)
//
#include <hip/hip_runtime.h>
#include <math.h>

#define NL   4
#define DIM  256
#define NH   8
#define HDIM 32
#define SQL  1024
#define SKL  1024
#define FFD  768
#define CB   4              // combined batch: 2 stacks * 2 batch
#define ROWS (CB * SQL)     // 4096

typedef __attribute__((ext_vector_type(8))) short bf16x8;
typedef __attribute__((ext_vector_type(4))) short bf16x4;
typedef __attribute__((ext_vector_type(4))) float f32x4;
typedef __attribute__((ext_vector_type(2))) float f32x2;

// ---------------------------------------------------------------- utilities

__device__ __forceinline__ short f2bf(float f) {
    union { float f; unsigned u; } v; v.f = f;
    unsigned u = v.u + 0x7fffu + ((v.u >> 16) & 1u);   // RNE
    return (short)(u >> 16);
}

// mish(x) = x*tanh(softplus(x)) = x*(u^2+2u)/(u^2+2u+2), u = e^x.
__device__ __forceinline__ float fast_mish(float x) {
    float u = __expf(fminf(x, 20.0f));
    float a = __builtin_fmaf(u, u, 2.0f * u);          // u^2 + 2u
    return x * a * __builtin_amdgcn_rcpf(a + 2.0f);
}

__device__ __forceinline__ f32x2 lo2(f32x4 v) { return __builtin_shufflevector(v, v, 0, 1); }
__device__ __forceinline__ f32x2 hi2(f32x4 v) { return __builtin_shufflevector(v, v, 2, 3); }

// ---------------------------------------------------------------- init

__global__ __launch_bounds__(256) void init_kernel(
        const float* __restrict__ pose, const float* __restrict__ vel,
        const float* __restrict__ img, float* __restrict__ X,
        short* __restrict__ Xb, short* __restrict__ KVb) {
    int idx = blockIdx.x * 256 + threadIdx.x;
    if (idx >= CB * SQL * DIM) return;
    int c = idx / (SQL * DIM);
    int rem = idx - c * (SQL * DIM);
    int b = c & 1;
    float pv = pose[b * SQL * DIM + rem];
    X[idx]  = pv;
    Xb[idx] = f2bf(pv);
    const float* kv = (c < 2) ? vel : img;
    KVb[idx] = f2bf(kv[b * SQL * DIM + rem]);
}

// ---------------------------------------------------------------- merged weight transpose
// 640 blocks: z<256 QKVO (4 mats x 4 layers x 16 tiles), z<448 W1, else W2.

__global__ __launch_bounds__(256) void transpose_all(
        const float* __restrict__ Wq, const float* __restrict__ Wk,
        const float* __restrict__ Wv, const float* __restrict__ Wo,
        const float* __restrict__ W1, const float* __restrict__ W2,
        short* __restrict__ Wqt, short* __restrict__ Wkt,
        short* __restrict__ Wvt, short* __restrict__ Wot,
        short* __restrict__ W1t, short* __restrict__ W2t) {
    __shared__ float tile[64][65];
    int z = blockIdx.x;
    const float* src; short* dst; int K, N, tx, ty;
    if (z < 256) {
        int m = z >> 6, lyr = (z >> 4) & 3, r = z & 15;
        src = ((m == 0) ? Wq : (m == 1) ? Wk : (m == 2) ? Wv : Wo) + (size_t)lyr * DIM * DIM;
        dst = ((m == 0) ? Wqt : (m == 1) ? Wkt : (m == 2) ? Wvt : Wot) + (size_t)lyr * DIM * DIM;
        K = DIM; N = DIM; tx = r & 3; ty = r >> 2;
    } else if (z < 448) {
        int idx = z - 256, lyr = idx / 48, r = idx % 48;
        src = W1 + (size_t)lyr * DIM * FFD; dst = W1t + (size_t)lyr * DIM * FFD;
        K = DIM; N = FFD; tx = r % 12; ty = r / 12;
    } else {
        int idx = z - 448, lyr = idx / 48, r = idx % 48;
        src = W2 + (size_t)lyr * FFD * DIM; dst = W2t + (size_t)lyr * FFD * DIM;
        K = FFD; N = DIM; tx = r % 4; ty = r / 4;
    }
    int t = threadIdx.x;
    int n0 = tx * 64, k0 = ty * 64;
#pragma unroll
    for (int i = 0; i < 16; i++) {
        int idx = t + i * 256;
        int r = idx >> 6, c = idx & 63;
        tile[r][c] = src[(size_t)(k0 + r) * N + n0 + c];
    }
    __syncthreads();
#pragma unroll
    for (int i = 0; i < 16; i++) {
        int idx = t + i * 256;
        int r = idx >> 6, c = idx & 63;
        dst[(size_t)(n0 + r) * K + k0 + c] = f2bf(tile[c][r]);
    }
}

// ---------------------------------------------------------------- upfront K/V batch
// All 4 layers' K and V projections (input KVb is layer-invariant).
// grid (DIM/64, ROWS/64, 8): z = lyr*2 + {0:K, 1:V}.

__global__ __launch_bounds__(256) void kv_gemm(
        const short* __restrict__ KVb, const short* __restrict__ Wkt,
        const short* __restrict__ Wvt, const float* __restrict__ bk,
        const float* __restrict__ bv, short* __restrict__ Kb4,
        short* __restrict__ Vt4) {
    int z = blockIdx.z, lyr = z >> 1, kv = z & 1;
    const short* Wt   = (kv ? Wvt : Wkt) + (size_t)lyr * DIM * DIM;
    const float* bias = (kv ? bv : bk) + (size_t)lyr * DIM;

    int t = threadIdx.x, l = t & 63, w = t >> 6;
    int lq = l & 15, lg = l >> 4;
    int bm = blockIdx.y * 64, bn = blockIdx.x * 64;

    const short* ap = KVb + (size_t)(bm + w * 16 + lq) * DIM + lg * 8;
    const short* wp = Wt + (size_t)(bn + lq) * DIM + lg * 8;

    f32x4 acc[4];
#pragma unroll
    for (int nt = 0; nt < 4; nt++) acc[nt] = (f32x4){0.f, 0.f, 0.f, 0.f};
#pragma unroll
    for (int k0 = 0; k0 < DIM; k0 += 32) {
        bf16x8 af = *(const bf16x8*)(ap + k0);
#pragma unroll
        for (int nt = 0; nt < 4; nt++) {
            bf16x8 bfr = *(const bf16x8*)(wp + (size_t)nt * 16 * DIM + k0);
            acc[nt] = __builtin_amdgcn_mfma_f32_16x16x32_bf16(af, bfr, acc[nt], 0, 0, 0);
        }
    }

    int ms = bm + w * 16 + lg * 4;
#pragma unroll
    for (int nt = 0; nt < 4; nt++) {
        int col = bn + nt * 16 + lq;
        float bv_ = bias[col];
        if (kv == 0) {
            short* out = Kb4 + (size_t)lyr * ROWS * DIM;
#pragma unroll
            for (int j = 0; j < 4; j++)
                out[(size_t)(ms + j) * DIM + col] = f2bf(acc[nt][j] + bv_);
        } else {
            int cc = ms >> 10, kl = ms & 1023;
            bf16x4 pk;
#pragma unroll
            for (int j = 0; j < 4; j++) pk[j] = f2bf(acc[nt][j] + bv_);
            *(bf16x4*)(Vt4 + (size_t)lyr * ROWS * DIM + ((size_t)(cc * DIM + col)) * SKL + kl) = pk;
        }
    }
}

// ---------------------------------------------------------------- fused tail
// 8-row tiles, 256 thr, grid ROWS/8 = 512 -> 2 blocks/CU so phases of
// independent blocks overlap. MFMA A-frags duplicate the 8 rows (lq&7);
// lanes lg>=2 hold duplicate C rows and skip stores.
// G = T1b@Wo + bo; x1 = X + LN(G)*ag+ab; y = LN(x1)*fg+fb;
// g1 = mish(y@W1+b1); x2 = g1@W2 + b2 + x1; out = X + LN(x2)*g+b.

__global__ __launch_bounds__(256) void fused_tail(
        const short* __restrict__ T1b, const short* __restrict__ Wot,
        const float* __restrict__ bo, const float* __restrict__ Xres,
        const float* __restrict__ ag, const float* __restrict__ ab,
        const float* __restrict__ fg, const float* __restrict__ fb,
        const short* __restrict__ W1t, const float* __restrict__ b1,
        const short* __restrict__ W2t, const float* __restrict__ b2,
        const float* __restrict__ g_, const float* __restrict__ b_,
        float* __restrict__ outf, short* __restrict__ outb) {
    __shared__ float gbuf[8][264];                      // G, then x1 (kept to phase E)
    __shared__ __align__(16) short y_lds[8][280];       // y bf16
    __shared__ __align__(16) short g1[8][792];          // mish out bf16
    float (*xbuf)[264] = (float(*)[264])g1;             // x2 fp32, aliases g1 after phase D

    int t = threadIdx.x, l = t & 63, w = t >> 6;        // w: 0..3
    int lq = l & 15, lg = l >> 4;
    int bm = blockIdx.x * 8;
    int arow = bm + (lq & 7);                           // duplicated A row

    // ---- phase A: out-proj, wave w -> cols [64w, 64w+64)
    {
        const short* ap = T1b + (size_t)arow * DIM + lg * 8;
        const short* wp = Wot + (size_t)(w * 64 + lq) * DIM + lg * 8;
        f32x4 acc[4];
#pragma unroll
        for (int nt = 0; nt < 4; nt++) acc[nt] = (f32x4){0.f, 0.f, 0.f, 0.f};
#pragma unroll
        for (int k0 = 0; k0 < DIM; k0 += 32) {
            bf16x8 af = *(const bf16x8*)(ap + k0);
#pragma unroll
            for (int nt = 0; nt < 4; nt++) {
                bf16x8 bfr = *(const bf16x8*)(wp + (size_t)nt * 16 * DIM + k0);
                acc[nt] = __builtin_amdgcn_mfma_f32_16x16x32_bf16(af, bfr, acc[nt], 0, 0, 0);
            }
        }
        if (lg < 2) {
#pragma unroll
            for (int nt = 0; nt < 4; nt++) {
                int col = w * 64 + nt * 16 + lq;
                float bv_ = bo[col];
#pragma unroll
                for (int j = 0; j < 4; j++) gbuf[lg * 4 + j][col] = acc[nt][j] + bv_;
            }
        }
    }
    __syncthreads();

    // ---- phase B: LN(G)+res -> x1 (in gbuf); LN(x1) -> y_lds bf16
    {
        int g = t >> 5, u = t & 31;                     // 8 rows x 32 lanes
        int row = bm + g;
        float s = 0.f, s2 = 0.f;
#pragma unroll
        for (int i = 0; i < 8; i++) {
            float v = gbuf[g][u + 32 * i];
            s += v; s2 += v * v;
        }
#pragma unroll
        for (int off = 1; off < 32; off <<= 1) { s += __shfl_xor(s, off); s2 += __shfl_xor(s2, off); }
        float m = s * (1.f / DIM);
        float rstd = rsqrtf(s2 * (1.f / DIM) - m * m + 1e-5f);

        float x1v[8];
        float sb = 0.f, sb2 = 0.f;
#pragma unroll
        for (int i = 0; i < 8; i++) {
            int col = u + 32 * i;
            float x1 = Xres[(size_t)row * DIM + col] + (gbuf[g][col] - m) * rstd * ag[col] + ab[col];
            x1v[i] = x1; sb += x1; sb2 += x1 * x1;
        }
#pragma unroll
        for (int off = 1; off < 32; off <<= 1) { sb += __shfl_xor(sb, off); sb2 += __shfl_xor(sb2, off); }
        float m2 = sb * (1.f / DIM);
        float rstd2 = rsqrtf(sb2 * (1.f / DIM) - m2 * m2 + 1e-5f);
#pragma unroll
        for (int i = 0; i < 8; i++) {
            int col = u + 32 * i;
            gbuf[g][col]  = x1v[i];                     // keep x1
            y_lds[g][col] = f2bf((x1v[i] - m2) * rstd2 * fg[col] + fb[col]);
        }
    }
    __syncthreads();

    // ---- phase C: g1 = mish(y@W1+b1); wave w -> cols [192w, 192w+192)
    {
        const short* wp = W1t + (size_t)(w * 192 + lq) * DIM + lg * 8;
        f32x4 acc[12];
#pragma unroll
        for (int nt = 0; nt < 12; nt++) acc[nt] = (f32x4){0.f, 0.f, 0.f, 0.f};
#pragma unroll
        for (int k0 = 0; k0 < DIM; k0 += 32) {
            bf16x8 af = *(const bf16x8*)(&y_lds[lq & 7][k0 + lg * 8]);
#pragma unroll
            for (int nt = 0; nt < 12; nt++) {
                bf16x8 bfr = *(const bf16x8*)(wp + (size_t)nt * 16 * DIM + k0);
                acc[nt] = __builtin_amdgcn_mfma_f32_16x16x32_bf16(af, bfr, acc[nt], 0, 0, 0);
            }
        }
        if (lg < 2) {
#pragma unroll
            for (int nt = 0; nt < 12; nt++) {
                int col = w * 192 + nt * 16 + lq;
                float bv_ = b1[col];
#pragma unroll
                for (int j = 0; j < 4; j++)
                    g1[lg * 4 + j][col] = f2bf(fast_mish(acc[nt][j] + bv_));
            }
        }
    }
    __syncthreads();

    // ---- phase D: x2 = g1@W2 + b2 + x1; wave w -> cols [64w, 64w+64), K=768
    f32x4 acc2[4];
#pragma unroll
    for (int nt = 0; nt < 4; nt++) acc2[nt] = (f32x4){0.f, 0.f, 0.f, 0.f};
    {
        const short* wp2 = W2t + (size_t)(w * 64 + lq) * FFD + lg * 8;
#pragma unroll 6
        for (int ks = 0; ks < 24; ks++) {
            bf16x8 af = *(const bf16x8*)(&g1[lq & 7][ks * 32 + lg * 8]);
#pragma unroll
            for (int nt = 0; nt < 4; nt++) {
                bf16x8 bfr = *(const bf16x8*)(wp2 + (size_t)nt * 16 * FFD + ks * 32);
                acc2[nt] = __builtin_amdgcn_mfma_f32_16x16x32_bf16(af, bfr, acc2[nt], 0, 0, 0);
            }
        }
    }
    __syncthreads();   // all g1 reads done; xbuf may alias now
    if (lg < 2) {
#pragma unroll
        for (int nt = 0; nt < 4; nt++) {
            int col = w * 64 + nt * 16 + lq;
            float bv_ = b2[col];
#pragma unroll
            for (int j = 0; j < 4; j++)
                xbuf[lg * 4 + j][col] = acc2[nt][j] + bv_ + gbuf[lg * 4 + j][col];
        }
    }
    __syncthreads();

    // ---- phase E: out = X + LN(x2)*g+b
    {
        int g = t >> 5, u = t & 31;
        int row = bm + g;
        float s = 0.f, s2 = 0.f;
#pragma unroll
        for (int i = 0; i < 8; i++) {
            float v = xbuf[g][u + 32 * i];
            s += v; s2 += v * v;
        }
#pragma unroll
        for (int off = 1; off < 32; off <<= 1) { s += __shfl_xor(s, off); s2 += __shfl_xor(s2, off); }
        float m = s * (1.f / DIM);
        float rstd = rsqrtf(s2 * (1.f / DIM) - m * m + 1e-5f);
#pragma unroll
        for (int i = 0; i < 8; i++) {
            int col = u + 32 * i;
            float o = Xres[(size_t)row * DIM + col] + (xbuf[g][col] - m) * rstd * g_[col] + b_[col];
            outf[(size_t)row * DIM + col] = o;
            if (outb) outb[(size_t)row * DIM + col] = f2bf(o);
        }
    }
}

// ---------------------------------------------------------------- attention
// 256 thr = 4 waves; wave w owns k in [256w, 256w+256), acc[16]. Q in-kernel.
// Solver: full-support round 1 (no max) + dynamic NEWTON rounds (convex f,
// monotone from below, no overshoot) with early exit, cap 8. Exchange is one
// f32x2 (Sy, Sy2) per round. p_lds [4][16][256] swizzled; obuf aliases p_lds.

__global__ __launch_bounds__(256, 4) void attn_mfma(
        const short* __restrict__ Xb, const short* __restrict__ Wqt,
        const float* __restrict__ bq, const short* __restrict__ K,
        const short* __restrict__ Vt, short* __restrict__ O, float qscale) {
    int id = blockIdx.x;
    int xcd = id & 7, rest = id >> 3;          // rest: 0..255
    int hc = xcd * 4 + (rest >> 6);            // 0..31, bijective
    int c = hc & 3, h = hc >> 2;
    int qbase = (rest & 63) * 16;
    int t = threadIdx.x, l = t & 63, w = t >> 6;   // w: 0..3
    int lq = l & 15, lg = l >> 4;

    __shared__ __align__(16) short p_lds[4][16 * 256]; // 32KB; [wave][q][k] swizzled
    __shared__ __align__(16) short q_lds[16][40];      // Q tile bf16, padded rows
    __shared__ __align__(8) f32x2 sred2[2][4][16];     // [buf][wave][q] = {sy, sy2}
    float* obuf = (float*)p_lds;                       // [4][512], aliased after PV

    // ---- Q mini-GEMM: waves 0,1 compute d-range [16w, 16w+16) of this head
    if (w < 2) {
        const short* ap = Xb + (size_t)(c * SQL + qbase + lq) * DIM + lg * 8;
        const short* wp = Wqt + (size_t)(h * HDIM + w * 16 + lq) * DIM + lg * 8;
        f32x4 qa = {0.f, 0.f, 0.f, 0.f};
#pragma unroll
        for (int k0 = 0; k0 < DIM; k0 += 32) {
            bf16x8 af = *(const bf16x8*)(ap + k0);
            bf16x8 bfr = *(const bf16x8*)(wp + k0);
            qa = __builtin_amdgcn_mfma_f32_16x16x32_bf16(af, bfr, qa, 0, 0, 0);
        }
        float bb = bq[h * HDIM + w * 16 + lq];
#pragma unroll
        for (int j = 0; j < 4; j++)
            q_lds[lg * 4 + j][w * 16 + lq] = f2bf((qa[j] + bb) * qscale);
    }
    __syncthreads();
    bf16x8 qfrag = *(const bf16x8*)&q_lds[lq][lg * 8];

    // ---- QK^T: acc[kt][j] = S[k = 256w+16kt+4lg+j][q=lq]
    const int kw = w * 256;
    f32x4 acc[16];
#pragma unroll
    for (int kt = 0; kt < 16; kt++) {
        bf16x8 kf = *(const bf16x8*)(K + ((size_t)(c * SKL + kw + kt * 16 + lq)) * DIM + h * HDIM + lg * 8);
        f32x4 z = {0.f, 0.f, 0.f, 0.f};
        acc[kt] = __builtin_amdgcn_mfma_f32_16x16x32_bf16(kf, qfrag, z, 0, 0, 0);
    }

    const f32x2 z2 = {0.f, 0.f};
    float tau;

    // ---- round 1: full support, plain sums (no clipping, no max)
    {
        f32x2 S1 = z2, S2 = z2;
#pragma unroll
        for (int kt = 0; kt < 16; kt++) {
            f32x2 x0 = lo2(acc[kt]), x1 = hi2(acc[kt]);
            S1 += x0; S1 += x1;
            S2 += x0 * x0; S2 += x1 * x1;
        }
        float sy = S1.x + S1.y, sy2 = S2.x + S2.y;
        sy  += __shfl_xor(sy, 16);  sy  += __shfl_xor(sy, 32);
        sy2 += __shfl_xor(sy2, 16); sy2 += __shfl_xor(sy2, 32);
        if (l < 16) sred2[0][w][l] = (f32x2){sy, sy2};
        __syncthreads();
        f32x2 rr = sred2[0][0][lq] + sred2[0][1][lq] + sred2[0][2][lq] + sred2[0][3][lq];
        sy = rr.x; sy2 = rr.y;
        const float N = (float)SKL;
        float disc = fmaxf(sy * sy - N * (sy2 - 1.0f), 0.f);
        tau = (sy - sqrtf(disc)) * (1.0f / N);
    }

    // ---- dynamic Newton rounds: tau += (Sy2-1)/(2*Sy); monotone from below.
    int r = 0;
    for (;;) {
        int b = 1 - (r & 1);                   // buffers 1,0,1,0,... (round 1 used 0)
        f32x2 vt = {tau, tau};
        f32x2 S1 = z2, S2 = z2;
#pragma unroll
        for (int kt = 0; kt < 16; kt++) {
            f32x2 y0 = __builtin_elementwise_max(lo2(acc[kt]) - vt, z2);
            f32x2 y1 = __builtin_elementwise_max(hi2(acc[kt]) - vt, z2);
            S1 += y0; S1 += y1;
            S2 += y0 * y0; S2 += y1 * y1;
        }
        float sy = S1.x + S1.y, sy2 = S2.x + S2.y;
        sy  += __shfl_xor(sy, 16);  sy  += __shfl_xor(sy, 32);
        sy2 += __shfl_xor(sy2, 16); sy2 += __shfl_xor(sy2, 32);
        if (l < 16) sred2[b][w][l] = (f32x2){sy, sy2};
        __syncthreads();
        f32x2 rr = sred2[b][0][lq] + sred2[b][1][lq] + sred2[b][2][lq] + sred2[b][3][lq];
        sy = rr.x; sy2 = rr.y;
        float delta = (sy2 - 1.0f) / (2.0f * sy);
        tau += delta;
        r++;
        if (r >= 8 || __all(__builtin_fabsf(delta) < 1e-6f)) break;
    }

    // ---- p -> wave-private swizzled LDS (all 256 k), then PV
    f32x4 o0 = {0.f, 0.f, 0.f, 0.f}, o1 = {0.f, 0.f, 0.f, 0.f};
    const short* vbase0 = Vt + ((size_t)(c * DIM + h * HDIM + lq)) * SKL;
    const short* vbase1 = vbase0 + (size_t)16 * SKL;
    {
        f32x2 vt = {tau, tau};
        int swz = lq << 4;
#pragma unroll
        for (int kt = 0; kt < 16; kt++) {
            f32x2 y0 = __builtin_elementwise_max(lo2(acc[kt]) - vt, z2);
            f32x2 y1 = __builtin_elementwise_max(hi2(acc[kt]) - vt, z2);
            f32x2 p0 = y0 * y0, p1 = y1 * y1;
            unsigned u01, u23;
            asm("v_cvt_pk_bf16_f32 %0, %1, %2" : "=v"(u01) : "v"(p0.x), "v"(p0.y));
            asm("v_cvt_pk_bf16_f32 %0, %1, %2" : "=v"(u23) : "v"(p1.x), "v"(p1.y));
            int byte = lq * 512 + ((kt * 32 + lg * 8) ^ swz);
            *(uint2*)((char*)p_lds[w] + byte) = make_uint2(u01, u23);
        }
#pragma unroll
        for (int k2 = 0; k2 < 8; k2++) {
            int byte = lq * 512 + ((k2 * 64 + lg * 16) ^ swz);
            bf16x8 pa = *(const bf16x8*)((const char*)p_lds[w] + byte);
            int k0 = kw + k2 * 32 + lg * 8;
            bf16x8 vb0 = *(const bf16x8*)(vbase0 + k0);
            bf16x8 vb1 = *(const bf16x8*)(vbase1 + k0);
            o0 = __builtin_amdgcn_mfma_f32_16x16x32_bf16(pa, vb0, o0, 0, 0, 0);
            o1 = __builtin_amdgcn_mfma_f32_16x16x32_bf16(pa, vb1, o1, 0, 0, 0);
        }
    }
    __syncthreads();   // all p reads done; obuf may alias p_lds now

    // ---- cross-wave O reduce (4 partials): 256 threads x 2 packed elements
#pragma unroll
    for (int j = 0; j < 4; j++) {
        obuf[w * 512 + (lg * 4 + j) * 32 + lq]      = o0[j];
        obuf[w * 512 + (lg * 4 + j) * 32 + 16 + lq] = o1[j];
    }
    __syncthreads();
    {
        int e0 = t * 2;                        // 0..510, covers all 512 outputs
        int q = e0 >> 5, d = e0 & 31;
        f32x2 s = *(const f32x2*)&obuf[e0];
#pragma unroll
        for (int ww = 1; ww < 4; ww++) s += *(const f32x2*)&obuf[ww * 512 + e0];
        unsigned uo;
        asm("v_cvt_pk_bf16_f32 %0, %1, %2" : "=v"(uo) : "v"(s.x), "v"(s.y));
        *(unsigned*)(O + ((size_t)(c * SQL + qbase + q)) * DIM + h * HDIM + d) = uo;
    }
}

// ---------------------------------------------------------------- driver

extern "C" void kernel_launch(void* const* d_in, const int* in_sizes, int n_in,
                              void* d_out, int out_size, void* d_ws, size_t ws_size,
                              hipStream_t stream) {
    const float* pose = (const float*)d_in[0];
    const float* vel  = (const float*)d_in[1];
    const float* img  = (const float*)d_in[2];
    const float* Wq   = (const float*)d_in[3];
    const float* bq   = (const float*)d_in[4];
    const float* Wk   = (const float*)d_in[5];
    const float* bk   = (const float*)d_in[6];
    const float* Wv   = (const float*)d_in[7];
    const float* bv   = (const float*)d_in[8];
    const float* Wo   = (const float*)d_in[9];
    const float* bo   = (const float*)d_in[10];
    const float* an_g = (const float*)d_in[11];
    const float* an_b = (const float*)d_in[12];
    const float* W1   = (const float*)d_in[13];
    const float* b1   = (const float*)d_in[14];
    const float* W2   = (const float*)d_in[15];
    const float* b2   = (const float*)d_in[16];
    const float* fn_g = (const float*)d_in[17];
    const float* fn_b = (const float*)d_in[18];
    const float* n_g  = (const float*)d_in[19];
    const float* n_b  = (const float*)d_in[20];

    const size_t SZ = (size_t)ROWS * DIM;           // 1M elements
    float* X    = (float*)d_ws;                     // fp32 residual stream
    short* Xb   = (short*)(X + SZ);
    short* KVb  = Xb + SZ;
    short* T1b  = KVb + SZ;                         // attn out bf16
    short* Kb4  = T1b + SZ;                         // [L][4096][256] bf16
    short* Vt4  = Kb4 + (size_t)NL * SZ;            // [L][CB][DIM][SKL] bf16
    short* Wqt  = Vt4 + (size_t)NL * SZ;
    short* Wkt  = Wqt + (size_t)NL * DIM * DIM;
    short* Wvt  = Wkt + (size_t)NL * DIM * DIM;
    short* Wot  = Wvt + (size_t)NL * DIM * DIM;
    short* W1t  = Wot + (size_t)NL * DIM * DIM;     // [L][768][256]
    short* W2t  = W1t + (size_t)NL * DIM * FFD;     // [L][256][768]

    {
        int total = CB * SQL * DIM;
        init_kernel<<<(total + 255) / 256, 256, 0, stream>>>(pose, vel, img, X, Xb, KVb);
    }
    transpose_all<<<640, 256, 0, stream>>>(Wq, Wk, Wv, Wo, W1, W2,
                                           Wqt, Wkt, Wvt, Wot, W1t, W2t);
    kv_gemm<<<dim3(DIM / 64, ROWS / 64, 2 * NL), 256, 0, stream>>>(
        KVb, Wkt, Wvt, bk, bv, Kb4, Vt4);

    const float qscale = 0.08838834764831845f;      // 0.5 / sqrt(32)

    for (int i = 0; i < NL; i++) {
        const short* Wqt_i = Wqt + (size_t)i * DIM * DIM;
        const short* Wot_i = Wot + (size_t)i * DIM * DIM;
        const short* W1t_i = W1t + (size_t)i * DIM * FFD;
        const short* W2t_i = W2t + (size_t)i * DIM * FFD;

        attn_mfma<<<2048, 256, 0, stream>>>(
            Xb, Wqt_i, bq + i * DIM, Kb4 + (size_t)i * SZ, Vt4 + (size_t)i * SZ,
            T1b, qscale);

        float* outp  = (i == NL - 1) ? (float*)d_out : X;
        short* outbp = (i == NL - 1) ? nullptr : Xb;
        fused_tail<<<ROWS / 8, 256, 0, stream>>>(
            T1b, Wot_i, bo + i * DIM, X,
            an_g + i * DIM, an_b + i * DIM, fn_g + i * DIM, fn_b + i * DIM,
            W1t_i, b1 + i * FFD, W2t_i, b2 + i * DIM,
            n_g + i * DIM, n_b + i * DIM, outp, outbp);
    }

    (void)in_sizes; (void)n_in; (void)out_size; (void)ws_size;
}

// Round 16
// 397.721 us; speedup vs baseline: 1.1945x; 1.1945x over previous
//
#include <hip/hip_runtime.h>
#include <math.h>

#define NL   4
#define DIM  256
#define NH   8
#define HDIM 32
#define SQL  1024
#define SKL  1024
#define FFD  768
#define CB   4              // combined batch: 2 stacks * 2 batch
#define ROWS (CB * SQL)     // 4096

typedef __attribute__((ext_vector_type(8))) short bf16x8;
typedef __attribute__((ext_vector_type(4))) short bf16x4;
typedef __attribute__((ext_vector_type(4))) float f32x4;
typedef __attribute__((ext_vector_type(2))) float f32x2;

// ---------------------------------------------------------------- utilities

__device__ __forceinline__ short f2bf(float f) {
    union { float f; unsigned u; } v; v.f = f;
    unsigned u = v.u + 0x7fffu + ((v.u >> 16) & 1u);   // RNE
    return (short)(u >> 16);
}

// mish(x) = x*tanh(softplus(x)) = x*(u^2+2u)/(u^2+2u+2), u = e^x.
__device__ __forceinline__ float fast_mish(float x) {
    float u = __expf(fminf(x, 20.0f));
    float a = __builtin_fmaf(u, u, 2.0f * u);          // u^2 + 2u
    return x * a * __builtin_amdgcn_rcpf(a + 2.0f);
}

__device__ __forceinline__ f32x2 lo2(f32x4 v) { return __builtin_shufflevector(v, v, 0, 1); }
__device__ __forceinline__ f32x2 hi2(f32x4 v) { return __builtin_shufflevector(v, v, 2, 3); }

// ---------------------------------------------------------------- init

__global__ __launch_bounds__(256) void init_kernel(
        const float* __restrict__ pose, const float* __restrict__ vel,
        const float* __restrict__ img, float* __restrict__ X,
        short* __restrict__ Xb, short* __restrict__ KVb) {
    int idx = blockIdx.x * 256 + threadIdx.x;
    if (idx >= CB * SQL * DIM) return;
    int c = idx / (SQL * DIM);
    int rem = idx - c * (SQL * DIM);
    int b = c & 1;
    float pv = pose[b * SQL * DIM + rem];
    X[idx]  = pv;
    Xb[idx] = f2bf(pv);
    const float* kv = (c < 2) ? vel : img;
    KVb[idx] = f2bf(kv[b * SQL * DIM + rem]);
}

// ---------------------------------------------------------------- merged weight transpose
// 640 blocks: z<256 QKVO (4 mats x 4 layers x 16 tiles), z<448 W1, else W2.

__global__ __launch_bounds__(256) void transpose_all(
        const float* __restrict__ Wq, const float* __restrict__ Wk,
        const float* __restrict__ Wv, const float* __restrict__ Wo,
        const float* __restrict__ W1, const float* __restrict__ W2,
        short* __restrict__ Wqt, short* __restrict__ Wkt,
        short* __restrict__ Wvt, short* __restrict__ Wot,
        short* __restrict__ W1t, short* __restrict__ W2t) {
    __shared__ float tile[64][65];
    int z = blockIdx.x;
    const float* src; short* dst; int K, N, tx, ty;
    if (z < 256) {
        int m = z >> 6, lyr = (z >> 4) & 3, r = z & 15;
        src = ((m == 0) ? Wq : (m == 1) ? Wk : (m == 2) ? Wv : Wo) + (size_t)lyr * DIM * DIM;
        dst = ((m == 0) ? Wqt : (m == 1) ? Wkt : (m == 2) ? Wvt : Wot) + (size_t)lyr * DIM * DIM;
        K = DIM; N = DIM; tx = r & 3; ty = r >> 2;
    } else if (z < 448) {
        int idx = z - 256, lyr = idx / 48, r = idx % 48;
        src = W1 + (size_t)lyr * DIM * FFD; dst = W1t + (size_t)lyr * DIM * FFD;
        K = DIM; N = FFD; tx = r % 12; ty = r / 12;
    } else {
        int idx = z - 448, lyr = idx / 48, r = idx % 48;
        src = W2 + (size_t)lyr * FFD * DIM; dst = W2t + (size_t)lyr * FFD * DIM;
        K = FFD; N = DIM; tx = r % 4; ty = r / 4;
    }
    int t = threadIdx.x;
    int n0 = tx * 64, k0 = ty * 64;
#pragma unroll
    for (int i = 0; i < 16; i++) {
        int idx = t + i * 256;
        int r = idx >> 6, c = idx & 63;
        tile[r][c] = src[(size_t)(k0 + r) * N + n0 + c];
    }
    __syncthreads();
#pragma unroll
    for (int i = 0; i < 16; i++) {
        int idx = t + i * 256;
        int r = idx >> 6, c = idx & 63;
        dst[(size_t)(n0 + r) * K + k0 + c] = f2bf(tile[c][r]);
    }
}

// ---------------------------------------------------------------- upfront K/V batch
// All 4 layers' K and V projections (input KVb is layer-invariant).
// grid (DIM/64, ROWS/64, 8): z = lyr*2 + {0:K, 1:V}.

__global__ __launch_bounds__(256) void kv_gemm(
        const short* __restrict__ KVb, const short* __restrict__ Wkt,
        const short* __restrict__ Wvt, const float* __restrict__ bk,
        const float* __restrict__ bv, short* __restrict__ Kb4,
        short* __restrict__ Vt4) {
    int z = blockIdx.z, lyr = z >> 1, kv = z & 1;
    const short* Wt   = (kv ? Wvt : Wkt) + (size_t)lyr * DIM * DIM;
    const float* bias = (kv ? bv : bk) + (size_t)lyr * DIM;

    int t = threadIdx.x, l = t & 63, w = t >> 6;
    int lq = l & 15, lg = l >> 4;
    int bm = blockIdx.y * 64, bn = blockIdx.x * 64;

    const short* ap = KVb + (size_t)(bm + w * 16 + lq) * DIM + lg * 8;
    const short* wp = Wt + (size_t)(bn + lq) * DIM + lg * 8;

    f32x4 acc[4];
#pragma unroll
    for (int nt = 0; nt < 4; nt++) acc[nt] = (f32x4){0.f, 0.f, 0.f, 0.f};
#pragma unroll
    for (int k0 = 0; k0 < DIM; k0 += 32) {
        bf16x8 af = *(const bf16x8*)(ap + k0);
#pragma unroll
        for (int nt = 0; nt < 4; nt++) {
            bf16x8 bfr = *(const bf16x8*)(wp + (size_t)nt * 16 * DIM + k0);
            acc[nt] = __builtin_amdgcn_mfma_f32_16x16x32_bf16(af, bfr, acc[nt], 0, 0, 0);
        }
    }

    int ms = bm + w * 16 + lg * 4;
#pragma unroll
    for (int nt = 0; nt < 4; nt++) {
        int col = bn + nt * 16 + lq;
        float bv_ = bias[col];
        if (kv == 0) {
            short* out = Kb4 + (size_t)lyr * ROWS * DIM;
#pragma unroll
            for (int j = 0; j < 4; j++)
                out[(size_t)(ms + j) * DIM + col] = f2bf(acc[nt][j] + bv_);
        } else {
            int cc = ms >> 10, kl = ms & 1023;
            bf16x4 pk;
#pragma unroll
            for (int j = 0; j < 4; j++) pk[j] = f2bf(acc[nt][j] + bv_);
            *(bf16x4*)(Vt4 + (size_t)lyr * ROWS * DIM + ((size_t)(cc * DIM + col)) * SKL + kl) = pk;
        }
    }
}

// ---------------------------------------------------------------- fused tail (512 thr)
// G = T1b@Wo + bo; x1 = X + LN(G)*ag+ab; y = LN(x1)*fg+fb;
// g1 = mish(y@W1+b1); x2 = g1@W2 + b2 + x1; out = X + LN(x2)*g+b.

__global__ __launch_bounds__(512) void fused_tail(
        const short* __restrict__ T1b, const short* __restrict__ Wot,
        const float* __restrict__ bo, const float* __restrict__ Xres,
        const float* __restrict__ ag, const float* __restrict__ ab,
        const float* __restrict__ fg, const float* __restrict__ fb,
        const short* __restrict__ W1t, const float* __restrict__ b1,
        const short* __restrict__ W2t, const float* __restrict__ b2,
        const float* __restrict__ g_, const float* __restrict__ b_,
        float* __restrict__ outf, short* __restrict__ outb) {
    __shared__ float gbuf[16][264];                     // G, then x1 (kept to phase E)
    __shared__ __align__(16) short y_lds[16][280];      // y bf16
    __shared__ __align__(16) short g1[16][792];         // mish out bf16
    float (*xbuf)[264] = (float(*)[264])g1;             // x2 fp32, aliases g1 after phase D

    int t = threadIdx.x, l = t & 63, w = t >> 6;        // w: 0..7
    int lq = l & 15, lg = l >> 4;
    int bm = blockIdx.x * 16;

    // ---- phase A: out-proj, wave w -> cols [32w, 32w+32)
    {
        const short* ap = T1b + (size_t)(bm + lq) * DIM + lg * 8;
        const short* wp = Wot + (size_t)(w * 32 + lq) * DIM + lg * 8;
        f32x4 acc[2];
        acc[0] = (f32x4){0.f, 0.f, 0.f, 0.f};
        acc[1] = (f32x4){0.f, 0.f, 0.f, 0.f};
#pragma unroll
        for (int k0 = 0; k0 < DIM; k0 += 32) {
            bf16x8 af = *(const bf16x8*)(ap + k0);
#pragma unroll
            for (int nt = 0; nt < 2; nt++) {
                bf16x8 bfr = *(const bf16x8*)(wp + (size_t)nt * 16 * DIM + k0);
                acc[nt] = __builtin_amdgcn_mfma_f32_16x16x32_bf16(af, bfr, acc[nt], 0, 0, 0);
            }
        }
#pragma unroll
        for (int nt = 0; nt < 2; nt++) {
            int col = w * 32 + nt * 16 + lq;
            float bv_ = bo[col];
#pragma unroll
            for (int j = 0; j < 4; j++) gbuf[lg * 4 + j][col] = acc[nt][j] + bv_;
        }
    }
    __syncthreads();

    // ---- phase B: LN(G)+res -> x1 (in-place in gbuf); LN(x1) -> y_lds bf16
    {
        int g = t >> 5, u = t & 31;
        int row = bm + g;
        float s = 0.f, s2 = 0.f;
#pragma unroll
        for (int i = 0; i < 8; i++) {
            float v = gbuf[g][u + 32 * i];
            s += v; s2 += v * v;
        }
#pragma unroll
        for (int off = 1; off < 32; off <<= 1) { s += __shfl_xor(s, off); s2 += __shfl_xor(s2, off); }
        float m = s * (1.f / DIM);
        float rstd = rsqrtf(s2 * (1.f / DIM) - m * m + 1e-5f);

        float x1v[8];
        float sb = 0.f, sb2 = 0.f;
#pragma unroll
        for (int i = 0; i < 8; i++) {
            int col = u + 32 * i;
            float x1 = Xres[(size_t)row * DIM + col] + (gbuf[g][col] - m) * rstd * ag[col] + ab[col];
            x1v[i] = x1; sb += x1; sb2 += x1 * x1;
        }
#pragma unroll
        for (int off = 1; off < 32; off <<= 1) { sb += __shfl_xor(sb, off); sb2 += __shfl_xor(sb2, off); }
        float m2 = sb * (1.f / DIM);
        float rstd2 = rsqrtf(sb2 * (1.f / DIM) - m2 * m2 + 1e-5f);
#pragma unroll
        for (int i = 0; i < 8; i++) {
            int col = u + 32 * i;
            gbuf[g][col]  = x1v[i];                                   // keep x1
            y_lds[g][col] = f2bf((x1v[i] - m2) * rstd2 * fg[col] + fb[col]);
        }
    }
    __syncthreads();

    // ---- phase C: g1 = mish(y@W1+b1); wave w -> cols [96w, 96w+96)
    {
        const short* wp = W1t + (size_t)(w * 96 + lq) * DIM + lg * 8;
        f32x4 acc[6];
#pragma unroll
        for (int nt = 0; nt < 6; nt++) acc[nt] = (f32x4){0.f, 0.f, 0.f, 0.f};
#pragma unroll
        for (int k0 = 0; k0 < DIM; k0 += 32) {
            bf16x8 af = *(const bf16x8*)(&y_lds[lq][k0 + lg * 8]);
#pragma unroll
            for (int nt = 0; nt < 6; nt++) {
                bf16x8 bfr = *(const bf16x8*)(wp + (size_t)nt * 16 * DIM + k0);
                acc[nt] = __builtin_amdgcn_mfma_f32_16x16x32_bf16(af, bfr, acc[nt], 0, 0, 0);
            }
        }
#pragma unroll
        for (int nt = 0; nt < 6; nt++) {
            int col = w * 96 + nt * 16 + lq;
            float bv_ = b1[col];
#pragma unroll
            for (int j = 0; j < 4; j++)
                g1[lg * 4 + j][col] = f2bf(fast_mish(acc[nt][j] + bv_));
        }
    }
    __syncthreads();

    // ---- phase D: x2 = g1@W2 + b2 + x1; wave w -> cols [32w, 32w+32)
    f32x4 acc2[2];
    acc2[0] = (f32x4){0.f, 0.f, 0.f, 0.f};
    acc2[1] = (f32x4){0.f, 0.f, 0.f, 0.f};
    {
        const short* wp2 = W2t + (size_t)(w * 32 + lq) * FFD + lg * 8;
#pragma unroll 6
        for (int ks = 0; ks < 24; ks++) {
            bf16x8 af = *(const bf16x8*)(&g1[lq][ks * 32 + lg * 8]);
#pragma unroll
            for (int nt = 0; nt < 2; nt++) {
                bf16x8 bfr = *(const bf16x8*)(wp2 + (size_t)nt * 16 * FFD + ks * 32);
                acc2[nt] = __builtin_amdgcn_mfma_f32_16x16x32_bf16(af, bfr, acc2[nt], 0, 0, 0);
            }
        }
    }
    __syncthreads();   // all g1 reads done; xbuf may alias now
#pragma unroll
    for (int nt = 0; nt < 2; nt++) {
        int col = w * 32 + nt * 16 + lq;
        float bv_ = b2[col];
#pragma unroll
        for (int j = 0; j < 4; j++)
            xbuf[lg * 4 + j][col] = acc2[nt][j] + bv_ + gbuf[lg * 4 + j][col];
    }
    __syncthreads();

    // ---- phase E: out = X + LN(x2)*g+b
    {
        int g = t >> 5, u = t & 31;
        int row = bm + g;
        float s = 0.f, s2 = 0.f;
#pragma unroll
        for (int i = 0; i < 8; i++) {
            float v = xbuf[g][u + 32 * i];
            s += v; s2 += v * v;
        }
#pragma unroll
        for (int off = 1; off < 32; off <<= 1) { s += __shfl_xor(s, off); s2 += __shfl_xor(s2, off); }
        float m = s * (1.f / DIM);
        float rstd = rsqrtf(s2 * (1.f / DIM) - m * m + 1e-5f);
#pragma unroll
        for (int i = 0; i < 8; i++) {
            int col = u + 32 * i;
            float o = Xres[(size_t)row * DIM + col] + (xbuf[g][col] - m) * rstd * g_[col] + b_[col];
            outf[(size_t)row * DIM + col] = o;
            if (outb) outb[(size_t)row * DIM + col] = f2bf(o);
        }
    }
}

// ---------------------------------------------------------------- attention
// 512 thr = 8 waves; wave w owns k in [128w, 128w+128). Q computed in-kernel.
// Entmax: round 1 = full-support plain sums (no row-max), then DYNAMIC
// clipped Michelot rounds with early exit (cap 8). s_setprio around MFMA
// clusters (T5: helps when waves desynchronize at solver exit).
// p_lds [8][16][128] swizzled; obuf aliases p_lds.

__global__ __launch_bounds__(512, 6) void attn_mfma(
        const short* __restrict__ Xb, const short* __restrict__ Wqt,
        const float* __restrict__ bq, const short* __restrict__ K,
        const short* __restrict__ Vt, short* __restrict__ O, float qscale) {
    int id = blockIdx.x;
    int xcd = id & 7, rest = id >> 3;          // rest: 0..255
    int hc = xcd * 4 + (rest >> 6);            // 0..31, bijective
    int c = hc & 3, h = hc >> 2;
    int qbase = (rest & 63) * 16;
    int t = threadIdx.x, l = t & 63, w = t >> 6;   // w: 0..7
    int lq = l & 15, lg = l >> 4;

    __shared__ __align__(16) short p_lds[8][16 * 128]; // 32KB; [wave][q][k] swizzled
    __shared__ __align__(16) short q_lds[16][40];      // Q tile bf16, padded rows
    __shared__ float sred[2][3][8][16];                // [buf][qty][wave][q]
    float* obuf = (float*)p_lds;                       // [8][512], aliased after PV

    // ---- Q mini-GEMM: waves 0,1 compute d-range [16w, 16w+16) of this head
    if (w < 2) {
        const short* ap = Xb + (size_t)(c * SQL + qbase + lq) * DIM + lg * 8;
        const short* wp = Wqt + (size_t)(h * HDIM + w * 16 + lq) * DIM + lg * 8;
        f32x4 qa = {0.f, 0.f, 0.f, 0.f};
#pragma unroll
        for (int k0 = 0; k0 < DIM; k0 += 32) {
            bf16x8 af = *(const bf16x8*)(ap + k0);
            bf16x8 bfr = *(const bf16x8*)(wp + k0);
            qa = __builtin_amdgcn_mfma_f32_16x16x32_bf16(af, bfr, qa, 0, 0, 0);
        }
        float bb = bq[h * HDIM + w * 16 + lq];
#pragma unroll
        for (int j = 0; j < 4; j++)
            q_lds[lg * 4 + j][w * 16 + lq] = f2bf((qa[j] + bb) * qscale);
    }
    __syncthreads();
    bf16x8 qfrag = *(const bf16x8*)&q_lds[lq][lg * 8];

    // ---- QK^T: acc[kt][j] = S[k = 128w+16kt+4lg+j][q=lq]
    const int kw = w * 128;
    f32x4 acc[8];
    __builtin_amdgcn_s_setprio(1);
#pragma unroll
    for (int kt = 0; kt < 8; kt++) {
        bf16x8 kf = *(const bf16x8*)(K + ((size_t)(c * SKL + kw + kt * 16 + lq)) * DIM + h * HDIM + lg * 8);
        f32x4 z = {0.f, 0.f, 0.f, 0.f};
        acc[kt] = __builtin_amdgcn_mfma_f32_16x16x32_bf16(kf, qfrag, z, 0, 0, 0);
    }
    __builtin_amdgcn_s_setprio(0);

    const f32x2 z2  = {0.f, 0.f};
    const f32x2 big = {1e30f, 1e30f};
    const f32x2 one = {1.f, 1.f};
    float tau;

    // ---- round 1: full support, plain sums (no clipping, no max)
    {
        f32x2 S1 = z2, S2 = z2;
#pragma unroll
        for (int kt = 0; kt < 8; kt++) {
            f32x2 x0 = lo2(acc[kt]), x1 = hi2(acc[kt]);
            S1 += x0; S1 += x1;
            S2 += x0 * x0; S2 += x1 * x1;
        }
        float sy = S1.x + S1.y, sy2 = S2.x + S2.y;
        sy  += __shfl_xor(sy, 16);  sy  += __shfl_xor(sy, 32);
        sy2 += __shfl_xor(sy2, 16); sy2 += __shfl_xor(sy2, 32);
        if (l < 16) { sred[0][0][w][l] = sy; sred[0][1][w][l] = sy2; }
        __syncthreads();
        sy = sred[0][0][0][lq]; sy2 = sred[0][1][0][lq];
#pragma unroll
        for (int ww = 1; ww < 8; ww++) {
            sy  += sred[0][0][ww][lq];
            sy2 += sred[0][1][ww][lq];
        }
        const float N = (float)SKL;
        float disc = fmaxf(sy * sy - N * (sy2 - 1.0f), 0.f);
        tau = (sy - sqrtf(disc)) * (1.0f / N);
    }

    // ---- dynamic clipped Michelot rounds, early exit, cap 8
    int r = 0;
    for (;;) {
        int b = 1 - (r & 1);                   // buffers 1,0,1,0,... (round 1 used 0)
        f32x2 vt = {tau, tau};
        f32x2 S1 = z2, S2 = z2, NN = z2;
#pragma unroll
        for (int kt = 0; kt < 8; kt++) {
            f32x2 y0 = __builtin_elementwise_max(lo2(acc[kt]) - vt, z2);
            f32x2 y1 = __builtin_elementwise_max(hi2(acc[kt]) - vt, z2);
            S1 += y0; S1 += y1;
            S2 += y0 * y0; S2 += y1 * y1;
            NN += __builtin_elementwise_min(y0 * big, one);
            NN += __builtin_elementwise_min(y1 * big, one);
        }
        float sy = S1.x + S1.y, sy2 = S2.x + S2.y, nn = NN.x + NN.y;
        sy  += __shfl_xor(sy, 16);  sy  += __shfl_xor(sy, 32);
        sy2 += __shfl_xor(sy2, 16); sy2 += __shfl_xor(sy2, 32);
        nn  += __shfl_xor(nn, 16);  nn  += __shfl_xor(nn, 32);
        if (l < 16) { sred[b][0][w][l] = nn; sred[b][1][w][l] = sy; sred[b][2][w][l] = sy2; }
        __syncthreads();
        nn = sred[b][0][0][lq]; sy = sred[b][1][0][lq]; sy2 = sred[b][2][0][lq];
#pragma unroll
        for (int ww = 1; ww < 8; ww++) {
            nn  += sred[b][0][ww][lq];
            sy  += sred[b][1][ww][lq];
            sy2 += sred[b][2][ww][lq];
        }
        float disc = fmaxf(sy * sy - nn * (sy2 - 1.0f), 0.f);
        float delta = (sy - sqrtf(disc)) / nn;
        tau += delta;
        r++;
        if (r >= 8 || __all(delta < 1e-6f)) break;
    }

    // ---- p -> wave-private swizzled LDS (all 128 k), then PV
    f32x4 o0 = {0.f, 0.f, 0.f, 0.f}, o1 = {0.f, 0.f, 0.f, 0.f};
    const short* vbase0 = Vt + ((size_t)(c * DIM + h * HDIM + lq)) * SKL;
    const short* vbase1 = vbase0 + (size_t)16 * SKL;
    {
        f32x2 vt = {tau, tau};
        int swz = lq << 4;
#pragma unroll
        for (int kt = 0; kt < 8; kt++) {
            f32x2 y0 = __builtin_elementwise_max(lo2(acc[kt]) - vt, z2);
            f32x2 y1 = __builtin_elementwise_max(hi2(acc[kt]) - vt, z2);
            f32x2 p0 = y0 * y0, p1 = y1 * y1;
            unsigned u01, u23;
            asm("v_cvt_pk_bf16_f32 %0, %1, %2" : "=v"(u01) : "v"(p0.x), "v"(p0.y));
            asm("v_cvt_pk_bf16_f32 %0, %1, %2" : "=v"(u23) : "v"(p1.x), "v"(p1.y));
            int byte = lq * 256 + ((kt * 32 + lg * 8) ^ swz);
            *(uint2*)((char*)p_lds[w] + byte) = make_uint2(u01, u23);
        }
        __builtin_amdgcn_s_setprio(1);
#pragma unroll
        for (int k2 = 0; k2 < 4; k2++) {
            int byte = lq * 256 + ((k2 * 64 + lg * 16) ^ swz);
            bf16x8 pa = *(const bf16x8*)((const char*)p_lds[w] + byte);
            int k0 = kw + k2 * 32 + lg * 8;
            bf16x8 vb0 = *(const bf16x8*)(vbase0 + k0);
            bf16x8 vb1 = *(const bf16x8*)(vbase1 + k0);
            o0 = __builtin_amdgcn_mfma_f32_16x16x32_bf16(pa, vb0, o0, 0, 0, 0);
            o1 = __builtin_amdgcn_mfma_f32_16x16x32_bf16(pa, vb1, o1, 0, 0, 0);
        }
        __builtin_amdgcn_s_setprio(0);
    }
    __syncthreads();   // all p reads done; obuf may alias p_lds now

    // ---- cross-wave O reduce (8 partials): 256 threads x 2 packed elements
#pragma unroll
    for (int j = 0; j < 4; j++) {
        obuf[w * 512 + (lg * 4 + j) * 32 + lq]      = o0[j];
        obuf[w * 512 + (lg * 4 + j) * 32 + 16 + lq] = o1[j];
    }
    __syncthreads();
    if (t < 256) {
        int e0 = t * 2;                        // 0..510, covers all 512 outputs
        int q = e0 >> 5, d = e0 & 31;
        f32x2 s = *(const f32x2*)&obuf[e0];
#pragma unroll
        for (int ww = 1; ww < 8; ww++) s += *(const f32x2*)&obuf[ww * 512 + e0];
        unsigned uo;
        asm("v_cvt_pk_bf16_f32 %0, %1, %2" : "=v"(uo) : "v"(s.x), "v"(s.y));
        *(unsigned*)(O + ((size_t)(c * SQL + qbase + q)) * DIM + h * HDIM + d) = uo;
    }
}

// ---------------------------------------------------------------- driver

extern "C" void kernel_launch(void* const* d_in, const int* in_sizes, int n_in,
                              void* d_out, int out_size, void* d_ws, size_t ws_size,
                              hipStream_t stream) {
    const float* pose = (const float*)d_in[0];
    const float* vel  = (const float*)d_in[1];
    const float* img  = (const float*)d_in[2];
    const float* Wq   = (const float*)d_in[3];
    const float* bq   = (const float*)d_in[4];
    const float* Wk   = (const float*)d_in[5];
    const float* bk   = (const float*)d_in[6];
    const float* Wv   = (const float*)d_in[7];
    const float* bv   = (const float*)d_in[8];
    const float* Wo   = (const float*)d_in[9];
    const float* bo   = (const float*)d_in[10];
    const float* an_g = (const float*)d_in[11];
    const float* an_b = (const float*)d_in[12];
    const float* W1   = (const float*)d_in[13];
    const float* b1   = (const float*)d_in[14];
    const float* W2   = (const float*)d_in[15];
    const float* b2   = (const float*)d_in[16];
    const float* fn_g = (const float*)d_in[17];
    const float* fn_b = (const float*)d_in[18];
    const float* n_g  = (const float*)d_in[19];
    const float* n_b  = (const float*)d_in[20];

    const size_t SZ = (size_t)ROWS * DIM;           // 1M elements
    float* X    = (float*)d_ws;                     // fp32 residual stream
    short* Xb   = (short*)(X + SZ);
    short* KVb  = Xb + SZ;
    short* T1b  = KVb + SZ;                         // attn out bf16
    short* Kb4  = T1b + SZ;                         // [L][4096][256] bf16
    short* Vt4  = Kb4 + (size_t)NL * SZ;            // [L][CB][DIM][SKL] bf16
    short* Wqt  = Vt4 + (size_t)NL * SZ;
    short* Wkt  = Wqt + (size_t)NL * DIM * DIM;
    short* Wvt  = Wkt + (size_t)NL * DIM * DIM;
    short* Wot  = Wvt + (size_t)NL * DIM * DIM;
    short* W1t  = Wot + (size_t)NL * DIM * DIM;     // [L][768][256]
    short* W2t  = W1t + (size_t)NL * DIM * FFD;     // [L][256][768]

    {
        int total = CB * SQL * DIM;
        init_kernel<<<(total + 255) / 256, 256, 0, stream>>>(pose, vel, img, X, Xb, KVb);
    }
    transpose_all<<<640, 256, 0, stream>>>(Wq, Wk, Wv, Wo, W1, W2,
                                           Wqt, Wkt, Wvt, Wot, W1t, W2t);
    kv_gemm<<<dim3(DIM / 64, ROWS / 64, 2 * NL), 256, 0, stream>>>(
        KVb, Wkt, Wvt, bk, bv, Kb4, Vt4);

    const float qscale = 0.08838834764831845f;      // 0.5 / sqrt(32)

    for (int i = 0; i < NL; i++) {
        const short* Wqt_i = Wqt + (size_t)i * DIM * DIM;
        const short* Wot_i = Wot + (size_t)i * DIM * DIM;
        const short* W1t_i = W1t + (size_t)i * DIM * FFD;
        const short* W2t_i = W2t + (size_t)i * DIM * FFD;

        attn_mfma<<<2048, 512, 0, stream>>>(
            Xb, Wqt_i, bq + i * DIM, Kb4 + (size_t)i * SZ, Vt4 + (size_t)i * SZ,
            T1b, qscale);

        float* outp  = (i == NL - 1) ? (float*)d_out : X;
        short* outbp = (i == NL - 1) ? nullptr : Xb;
        fused_tail<<<ROWS / 16, 512, 0, stream>>>(
            T1b, Wot_i, bo + i * DIM, X,
            an_g + i * DIM, an_b + i * DIM, fn_g + i * DIM, fn_b + i * DIM,
            W1t_i, b1 + i * FFD, W2t_i, b2 + i * DIM,
            n_g + i * DIM, n_b + i * DIM, outp, outbp);
    }

    (void)in_sizes; (void)n_in; (void)out_size; (void)ws_size;
}

// Round 17
// 394.482 us; speedup vs baseline: 1.2043x; 1.0082x over previous
//
#include <hip/hip_runtime.h>
#include <math.h>

#define NL   4
#define DIM  256
#define NH   8
#define HDIM 32
#define SQL  1024
#define SKL  1024
#define FFD  768
#define CB   4              // combined batch: 2 stacks * 2 batch
#define ROWS (CB * SQL)     // 4096

typedef __attribute__((ext_vector_type(8))) short bf16x8;
typedef __attribute__((ext_vector_type(4))) short bf16x4;
typedef __attribute__((ext_vector_type(4))) float f32x4;
typedef __attribute__((ext_vector_type(2))) float f32x2;

// ---------------------------------------------------------------- utilities

__device__ __forceinline__ short f2bf(float f) {
    union { float f; unsigned u; } v; v.f = f;
    unsigned u = v.u + 0x7fffu + ((v.u >> 16) & 1u);   // RNE
    return (short)(u >> 16);
}

// mish(x) = x*tanh(softplus(x)) = x*(u^2+2u)/(u^2+2u+2), u = e^x.
__device__ __forceinline__ float fast_mish(float x) {
    float u = __expf(fminf(x, 20.0f));
    float a = __builtin_fmaf(u, u, 2.0f * u);          // u^2 + 2u
    return x * a * __builtin_amdgcn_rcpf(a + 2.0f);
}

__device__ __forceinline__ f32x2 lo2(f32x4 v) { return __builtin_shufflevector(v, v, 0, 1); }
__device__ __forceinline__ f32x2 hi2(f32x4 v) { return __builtin_shufflevector(v, v, 2, 3); }

// ---------------------------------------------------------------- init

__global__ __launch_bounds__(256) void init_kernel(
        const float* __restrict__ pose, const float* __restrict__ vel,
        const float* __restrict__ img, float* __restrict__ X,
        short* __restrict__ Xb, short* __restrict__ KVb) {
    int idx = blockIdx.x * 256 + threadIdx.x;
    if (idx >= CB * SQL * DIM) return;
    int c = idx / (SQL * DIM);
    int rem = idx - c * (SQL * DIM);
    int b = c & 1;
    float pv = pose[b * SQL * DIM + rem];
    X[idx]  = pv;
    Xb[idx] = f2bf(pv);
    const float* kv = (c < 2) ? vel : img;
    KVb[idx] = f2bf(kv[b * SQL * DIM + rem]);
}

// ---------------------------------------------------------------- merged weight transpose
// 640 blocks: z<256 QKVO (4 mats x 4 layers x 16 tiles), z<448 W1, else W2.

__global__ __launch_bounds__(256) void transpose_all(
        const float* __restrict__ Wq, const float* __restrict__ Wk,
        const float* __restrict__ Wv, const float* __restrict__ Wo,
        const float* __restrict__ W1, const float* __restrict__ W2,
        short* __restrict__ Wqt, short* __restrict__ Wkt,
        short* __restrict__ Wvt, short* __restrict__ Wot,
        short* __restrict__ W1t, short* __restrict__ W2t) {
    __shared__ float tile[64][65];
    int z = blockIdx.x;
    const float* src; short* dst; int K, N, tx, ty;
    if (z < 256) {
        int m = z >> 6, lyr = (z >> 4) & 3, r = z & 15;
        src = ((m == 0) ? Wq : (m == 1) ? Wk : (m == 2) ? Wv : Wo) + (size_t)lyr * DIM * DIM;
        dst = ((m == 0) ? Wqt : (m == 1) ? Wkt : (m == 2) ? Wvt : Wot) + (size_t)lyr * DIM * DIM;
        K = DIM; N = DIM; tx = r & 3; ty = r >> 2;
    } else if (z < 448) {
        int idx = z - 256, lyr = idx / 48, r = idx % 48;
        src = W1 + (size_t)lyr * DIM * FFD; dst = W1t + (size_t)lyr * DIM * FFD;
        K = DIM; N = FFD; tx = r % 12; ty = r / 12;
    } else {
        int idx = z - 448, lyr = idx / 48, r = idx % 48;
        src = W2 + (size_t)lyr * FFD * DIM; dst = W2t + (size_t)lyr * FFD * DIM;
        K = FFD; N = DIM; tx = r % 4; ty = r / 4;
    }
    int t = threadIdx.x;
    int n0 = tx * 64, k0 = ty * 64;
#pragma unroll
    for (int i = 0; i < 16; i++) {
        int idx = t + i * 256;
        int r = idx >> 6, c = idx & 63;
        tile[r][c] = src[(size_t)(k0 + r) * N + n0 + c];
    }
    __syncthreads();
#pragma unroll
    for (int i = 0; i < 16; i++) {
        int idx = t + i * 256;
        int r = idx >> 6, c = idx & 63;
        dst[(size_t)(n0 + r) * K + k0 + c] = f2bf(tile[c][r]);
    }
}

// ---------------------------------------------------------------- upfront K/V batch
// All 4 layers' K and V projections (input KVb is layer-invariant).
// grid (DIM/64, ROWS/64, 8): z = lyr*2 + {0:K, 1:V}.

__global__ __launch_bounds__(256) void kv_gemm(
        const short* __restrict__ KVb, const short* __restrict__ Wkt,
        const short* __restrict__ Wvt, const float* __restrict__ bk,
        const float* __restrict__ bv, short* __restrict__ Kb4,
        short* __restrict__ Vt4) {
    int z = blockIdx.z, lyr = z >> 1, kv = z & 1;
    const short* Wt   = (kv ? Wvt : Wkt) + (size_t)lyr * DIM * DIM;
    const float* bias = (kv ? bv : bk) + (size_t)lyr * DIM;

    int t = threadIdx.x, l = t & 63, w = t >> 6;
    int lq = l & 15, lg = l >> 4;
    int bm = blockIdx.y * 64, bn = blockIdx.x * 64;

    const short* ap = KVb + (size_t)(bm + w * 16 + lq) * DIM + lg * 8;
    const short* wp = Wt + (size_t)(bn + lq) * DIM + lg * 8;

    f32x4 acc[4];
#pragma unroll
    for (int nt = 0; nt < 4; nt++) acc[nt] = (f32x4){0.f, 0.f, 0.f, 0.f};
#pragma unroll
    for (int k0 = 0; k0 < DIM; k0 += 32) {
        bf16x8 af = *(const bf16x8*)(ap + k0);
#pragma unroll
        for (int nt = 0; nt < 4; nt++) {
            bf16x8 bfr = *(const bf16x8*)(wp + (size_t)nt * 16 * DIM + k0);
            acc[nt] = __builtin_amdgcn_mfma_f32_16x16x32_bf16(af, bfr, acc[nt], 0, 0, 0);
        }
    }

    int ms = bm + w * 16 + lg * 4;
#pragma unroll
    for (int nt = 0; nt < 4; nt++) {
        int col = bn + nt * 16 + lq;
        float bv_ = bias[col];
        if (kv == 0) {
            short* out = Kb4 + (size_t)lyr * ROWS * DIM;
#pragma unroll
            for (int j = 0; j < 4; j++)
                out[(size_t)(ms + j) * DIM + col] = f2bf(acc[nt][j] + bv_);
        } else {
            int cc = ms >> 10, kl = ms & 1023;
            bf16x4 pk;
#pragma unroll
            for (int j = 0; j < 4; j++) pk[j] = f2bf(acc[nt][j] + bv_);
            *(bf16x4*)(Vt4 + (size_t)lyr * ROWS * DIM + ((size_t)(cc * DIM + col)) * SKL + kl) = pk;
        }
    }
}

// ---------------------------------------------------------------- fused tail (512 thr)
// G = T1b@Wo + bo; x1 = X + LN(G)*ag+ab; y = LN(x1)*fg+fb;
// g1 = mish(y@W1+b1); x2 = g1@W2 + b2 + x1; out = X + LN(x2)*g+b.
// First-kstep weight frags for phases C and D prefetched at kernel top
// (addresses independent of earlier phases) to hide L2 latency.

__global__ __launch_bounds__(512) void fused_tail(
        const short* __restrict__ T1b, const short* __restrict__ Wot,
        const float* __restrict__ bo, const float* __restrict__ Xres,
        const float* __restrict__ ag, const float* __restrict__ ab,
        const float* __restrict__ fg, const float* __restrict__ fb,
        const short* __restrict__ W1t, const float* __restrict__ b1,
        const short* __restrict__ W2t, const float* __restrict__ b2,
        const float* __restrict__ g_, const float* __restrict__ b_,
        float* __restrict__ outf, short* __restrict__ outb) {
    __shared__ float gbuf[16][264];                     // G, then x1 (kept to phase E)
    __shared__ __align__(16) short y_lds[16][280];      // y bf16
    __shared__ __align__(16) short g1[16][792];         // mish out bf16
    float (*xbuf)[264] = (float(*)[264])g1;             // x2 fp32, aliases g1 after phase D

    int t = threadIdx.x, l = t & 63, w = t >> 6;        // w: 0..7
    int lq = l & 15, lg = l >> 4;
    int bm = blockIdx.x * 16;

    // ---- prefetch first-kstep weights for phases C and D
    const short* wpC = W1t + (size_t)(w * 96 + lq) * DIM + lg * 8;
    const short* wpD = W2t + (size_t)(w * 32 + lq) * FFD + lg * 8;
    bf16x8 cpre[6], dpre[2];
#pragma unroll
    for (int nt = 0; nt < 6; nt++) cpre[nt] = *(const bf16x8*)(wpC + (size_t)nt * 16 * DIM);
#pragma unroll
    for (int nt = 0; nt < 2; nt++) dpre[nt] = *(const bf16x8*)(wpD + (size_t)nt * 16 * FFD);

    // ---- phase A: out-proj, wave w -> cols [32w, 32w+32)
    {
        const short* ap = T1b + (size_t)(bm + lq) * DIM + lg * 8;
        const short* wp = Wot + (size_t)(w * 32 + lq) * DIM + lg * 8;
        f32x4 acc[2];
        acc[0] = (f32x4){0.f, 0.f, 0.f, 0.f};
        acc[1] = (f32x4){0.f, 0.f, 0.f, 0.f};
#pragma unroll
        for (int k0 = 0; k0 < DIM; k0 += 32) {
            bf16x8 af = *(const bf16x8*)(ap + k0);
#pragma unroll
            for (int nt = 0; nt < 2; nt++) {
                bf16x8 bfr = *(const bf16x8*)(wp + (size_t)nt * 16 * DIM + k0);
                acc[nt] = __builtin_amdgcn_mfma_f32_16x16x32_bf16(af, bfr, acc[nt], 0, 0, 0);
            }
        }
#pragma unroll
        for (int nt = 0; nt < 2; nt++) {
            int col = w * 32 + nt * 16 + lq;
            float bv_ = bo[col];
#pragma unroll
            for (int j = 0; j < 4; j++) gbuf[lg * 4 + j][col] = acc[nt][j] + bv_;
        }
    }
    __syncthreads();

    // ---- phase B: LN(G)+res -> x1 (in-place in gbuf); LN(x1) -> y_lds bf16
    {
        int g = t >> 5, u = t & 31;
        int row = bm + g;
        float s = 0.f, s2 = 0.f;
#pragma unroll
        for (int i = 0; i < 8; i++) {
            float v = gbuf[g][u + 32 * i];
            s += v; s2 += v * v;
        }
#pragma unroll
        for (int off = 1; off < 32; off <<= 1) { s += __shfl_xor(s, off); s2 += __shfl_xor(s2, off); }
        float m = s * (1.f / DIM);
        float rstd = rsqrtf(s2 * (1.f / DIM) - m * m + 1e-5f);

        float x1v[8];
        float sb = 0.f, sb2 = 0.f;
#pragma unroll
        for (int i = 0; i < 8; i++) {
            int col = u + 32 * i;
            float x1 = Xres[(size_t)row * DIM + col] + (gbuf[g][col] - m) * rstd * ag[col] + ab[col];
            x1v[i] = x1; sb += x1; sb2 += x1 * x1;
        }
#pragma unroll
        for (int off = 1; off < 32; off <<= 1) { sb += __shfl_xor(sb, off); sb2 += __shfl_xor(sb2, off); }
        float m2 = sb * (1.f / DIM);
        float rstd2 = rsqrtf(sb2 * (1.f / DIM) - m2 * m2 + 1e-5f);
#pragma unroll
        for (int i = 0; i < 8; i++) {
            int col = u + 32 * i;
            gbuf[g][col]  = x1v[i];                                   // keep x1
            y_lds[g][col] = f2bf((x1v[i] - m2) * rstd2 * fg[col] + fb[col]);
        }
    }
    __syncthreads();

    // ---- phase C: g1 = mish(y@W1+b1); wave w -> cols [96w, 96w+96)
    {
        f32x4 acc[6];
#pragma unroll
        for (int nt = 0; nt < 6; nt++) acc[nt] = (f32x4){0.f, 0.f, 0.f, 0.f};
        {   // k0 = 0 uses prefetched frags
            bf16x8 af = *(const bf16x8*)(&y_lds[lq][lg * 8]);
#pragma unroll
            for (int nt = 0; nt < 6; nt++)
                acc[nt] = __builtin_amdgcn_mfma_f32_16x16x32_bf16(af, cpre[nt], acc[nt], 0, 0, 0);
        }
#pragma unroll
        for (int k0 = 32; k0 < DIM; k0 += 32) {
            bf16x8 af = *(const bf16x8*)(&y_lds[lq][k0 + lg * 8]);
#pragma unroll
            for (int nt = 0; nt < 6; nt++) {
                bf16x8 bfr = *(const bf16x8*)(wpC + (size_t)nt * 16 * DIM + k0);
                acc[nt] = __builtin_amdgcn_mfma_f32_16x16x32_bf16(af, bfr, acc[nt], 0, 0, 0);
            }
        }
#pragma unroll
        for (int nt = 0; nt < 6; nt++) {
            int col = w * 96 + nt * 16 + lq;
            float bv_ = b1[col];
#pragma unroll
            for (int j = 0; j < 4; j++)
                g1[lg * 4 + j][col] = f2bf(fast_mish(acc[nt][j] + bv_));
        }
    }
    __syncthreads();

    // ---- phase D: x2 = g1@W2 + b2 + x1; wave w -> cols [32w, 32w+32), K=768
    f32x4 acc2[2];
    acc2[0] = (f32x4){0.f, 0.f, 0.f, 0.f};
    acc2[1] = (f32x4){0.f, 0.f, 0.f, 0.f};
    {
        {   // ks = 0 uses prefetched frags
            bf16x8 af = *(const bf16x8*)(&g1[lq][lg * 8]);
#pragma unroll
            for (int nt = 0; nt < 2; nt++)
                acc2[nt] = __builtin_amdgcn_mfma_f32_16x16x32_bf16(af, dpre[nt], acc2[nt], 0, 0, 0);
        }
#pragma unroll 6
        for (int ks = 1; ks < 24; ks++) {
            bf16x8 af = *(const bf16x8*)(&g1[lq][ks * 32 + lg * 8]);
#pragma unroll
            for (int nt = 0; nt < 2; nt++) {
                bf16x8 bfr = *(const bf16x8*)(wpD + (size_t)nt * 16 * FFD + ks * 32);
                acc2[nt] = __builtin_amdgcn_mfma_f32_16x16x32_bf16(af, bfr, acc2[nt], 0, 0, 0);
            }
        }
    }
    __syncthreads();   // all g1 reads done; xbuf may alias now
#pragma unroll
    for (int nt = 0; nt < 2; nt++) {
        int col = w * 32 + nt * 16 + lq;
        float bv_ = b2[col];
#pragma unroll
        for (int j = 0; j < 4; j++)
            xbuf[lg * 4 + j][col] = acc2[nt][j] + bv_ + gbuf[lg * 4 + j][col];
    }
    __syncthreads();

    // ---- phase E: out = X + LN(x2)*g+b
    {
        int g = t >> 5, u = t & 31;
        int row = bm + g;
        float s = 0.f, s2 = 0.f;
#pragma unroll
        for (int i = 0; i < 8; i++) {
            float v = xbuf[g][u + 32 * i];
            s += v; s2 += v * v;
        }
#pragma unroll
        for (int off = 1; off < 32; off <<= 1) { s += __shfl_xor(s, off); s2 += __shfl_xor(s2, off); }
        float m = s * (1.f / DIM);
        float rstd = rsqrtf(s2 * (1.f / DIM) - m * m + 1e-5f);
#pragma unroll
        for (int i = 0; i < 8; i++) {
            int col = u + 32 * i;
            float o = Xres[(size_t)row * DIM + col] + (xbuf[g][col] - m) * rstd * g_[col] + b_[col];
            outf[(size_t)row * DIM + col] = o;
            if (outb) outb[(size_t)row * DIM + col] = f2bf(o);
        }
    }
}

// ---------------------------------------------------------------- attention
// 512 thr = 8 waves; wave w owns k in [128w, 128w+128). Q computed in-kernel.
// Entmax: round 1 = full-support plain sums (no row-max), then DYNAMIC
// clipped Michelot rounds with early exit (cap 8). Solver exchange packed
// as f32x4 {nn,sy,sy2,-}: 8 ds_read_b128 instead of 24 scalar reads.
// p_lds [8][16][128] swizzled; obuf aliases p_lds.

__global__ __launch_bounds__(512, 6) void attn_mfma(
        const short* __restrict__ Xb, const short* __restrict__ Wqt,
        const float* __restrict__ bq, const short* __restrict__ K,
        const short* __restrict__ Vt, short* __restrict__ O, float qscale) {
    int id = blockIdx.x;
    int xcd = id & 7, rest = id >> 3;          // rest: 0..255
    int hc = xcd * 4 + (rest >> 6);            // 0..31, bijective
    int c = hc & 3, h = hc >> 2;
    int qbase = (rest & 63) * 16;
    int t = threadIdx.x, l = t & 63, w = t >> 6;   // w: 0..7
    int lq = l & 15, lg = l >> 4;

    __shared__ __align__(16) short p_lds[8][16 * 128]; // 32KB; [wave][q][k] swizzled
    __shared__ __align__(16) short q_lds[16][40];      // Q tile bf16, padded rows
    __shared__ __align__(16) f32x4 sred4[2][8][16];    // [buf][wave][q] = {nn,sy,sy2,-}
    float* obuf = (float*)p_lds;                       // [8][512], aliased after PV

    // ---- Q mini-GEMM: waves 0,1 compute d-range [16w, 16w+16) of this head
    if (w < 2) {
        const short* ap = Xb + (size_t)(c * SQL + qbase + lq) * DIM + lg * 8;
        const short* wp = Wqt + (size_t)(h * HDIM + w * 16 + lq) * DIM + lg * 8;
        f32x4 qa = {0.f, 0.f, 0.f, 0.f};
#pragma unroll
        for (int k0 = 0; k0 < DIM; k0 += 32) {
            bf16x8 af = *(const bf16x8*)(ap + k0);
            bf16x8 bfr = *(const bf16x8*)(wp + k0);
            qa = __builtin_amdgcn_mfma_f32_16x16x32_bf16(af, bfr, qa, 0, 0, 0);
        }
        float bb = bq[h * HDIM + w * 16 + lq];
#pragma unroll
        for (int j = 0; j < 4; j++)
            q_lds[lg * 4 + j][w * 16 + lq] = f2bf((qa[j] + bb) * qscale);
    }
    __syncthreads();
    bf16x8 qfrag = *(const bf16x8*)&q_lds[lq][lg * 8];

    // ---- QK^T: acc[kt][j] = S[k = 128w+16kt+4lg+j][q=lq]
    const int kw = w * 128;
    f32x4 acc[8];
#pragma unroll
    for (int kt = 0; kt < 8; kt++) {
        bf16x8 kf = *(const bf16x8*)(K + ((size_t)(c * SKL + kw + kt * 16 + lq)) * DIM + h * HDIM + lg * 8);
        f32x4 z = {0.f, 0.f, 0.f, 0.f};
        acc[kt] = __builtin_amdgcn_mfma_f32_16x16x32_bf16(kf, qfrag, z, 0, 0, 0);
    }

    const f32x2 z2  = {0.f, 0.f};
    const f32x2 big = {1e30f, 1e30f};
    const f32x2 one = {1.f, 1.f};
    float tau;

    // ---- round 1: full support, plain sums (no clipping, no max)
    {
        f32x2 S1 = z2, S2 = z2;
#pragma unroll
        for (int kt = 0; kt < 8; kt++) {
            f32x2 x0 = lo2(acc[kt]), x1 = hi2(acc[kt]);
            S1 += x0; S1 += x1;
            S2 += x0 * x0; S2 += x1 * x1;
        }
        float sy = S1.x + S1.y, sy2 = S2.x + S2.y;
        sy  += __shfl_xor(sy, 16);  sy  += __shfl_xor(sy, 32);
        sy2 += __shfl_xor(sy2, 16); sy2 += __shfl_xor(sy2, 32);
        if (l < 16) sred4[0][w][l] = (f32x4){0.f, sy, sy2, 0.f};
        __syncthreads();
        f32x4 rr = sred4[0][0][lq];
#pragma unroll
        for (int ww = 1; ww < 8; ww++) rr += sred4[0][ww][lq];
        sy = rr[1]; sy2 = rr[2];
        const float N = (float)SKL;
        float disc = fmaxf(sy * sy - N * (sy2 - 1.0f), 0.f);
        tau = (sy - sqrtf(disc)) * (1.0f / N);
    }

    // ---- dynamic clipped Michelot rounds, early exit, cap 8
    int r = 0;
    for (;;) {
        int b = 1 - (r & 1);                   // buffers 1,0,1,0,... (round 1 used 0)
        f32x2 vt = {tau, tau};
        f32x2 S1 = z2, S2 = z2, NN = z2;
#pragma unroll
        for (int kt = 0; kt < 8; kt++) {
            f32x2 y0 = __builtin_elementwise_max(lo2(acc[kt]) - vt, z2);
            f32x2 y1 = __builtin_elementwise_max(hi2(acc[kt]) - vt, z2);
            S1 += y0; S1 += y1;
            S2 += y0 * y0; S2 += y1 * y1;
            NN += __builtin_elementwise_min(y0 * big, one);
            NN += __builtin_elementwise_min(y1 * big, one);
        }
        float sy = S1.x + S1.y, sy2 = S2.x + S2.y, nn = NN.x + NN.y;
        sy  += __shfl_xor(sy, 16);  sy  += __shfl_xor(sy, 32);
        sy2 += __shfl_xor(sy2, 16); sy2 += __shfl_xor(sy2, 32);
        nn  += __shfl_xor(nn, 16);  nn  += __shfl_xor(nn, 32);
        if (l < 16) sred4[b][w][l] = (f32x4){nn, sy, sy2, 0.f};
        __syncthreads();
        f32x4 rr = sred4[b][0][lq];
#pragma unroll
        for (int ww = 1; ww < 8; ww++) rr += sred4[b][ww][lq];
        nn = rr[0]; sy = rr[1]; sy2 = rr[2];
        float disc = fmaxf(sy * sy - nn * (sy2 - 1.0f), 0.f);
        float delta = (sy - sqrtf(disc)) / nn;
        tau += delta;
        r++;
        if (r >= 8 || __all(delta < 1e-6f)) break;
    }

    // ---- p -> wave-private swizzled LDS (all 128 k), then PV
    f32x4 o0 = {0.f, 0.f, 0.f, 0.f}, o1 = {0.f, 0.f, 0.f, 0.f};
    const short* vbase0 = Vt + ((size_t)(c * DIM + h * HDIM + lq)) * SKL;
    const short* vbase1 = vbase0 + (size_t)16 * SKL;
    {
        f32x2 vt = {tau, tau};
        int swz = lq << 4;
#pragma unroll
        for (int kt = 0; kt < 8; kt++) {
            f32x2 y0 = __builtin_elementwise_max(lo2(acc[kt]) - vt, z2);
            f32x2 y1 = __builtin_elementwise_max(hi2(acc[kt]) - vt, z2);
            f32x2 p0 = y0 * y0, p1 = y1 * y1;
            unsigned u01, u23;
            asm("v_cvt_pk_bf16_f32 %0, %1, %2" : "=v"(u01) : "v"(p0.x), "v"(p0.y));
            asm("v_cvt_pk_bf16_f32 %0, %1, %2" : "=v"(u23) : "v"(p1.x), "v"(p1.y));
            int byte = lq * 256 + ((kt * 32 + lg * 8) ^ swz);
            *(uint2*)((char*)p_lds[w] + byte) = make_uint2(u01, u23);
        }
#pragma unroll
        for (int k2 = 0; k2 < 4; k2++) {
            int byte = lq * 256 + ((k2 * 64 + lg * 16) ^ swz);
            bf16x8 pa = *(const bf16x8*)((const char*)p_lds[w] + byte);
            int k0 = kw + k2 * 32 + lg * 8;
            bf16x8 vb0 = *(const bf16x8*)(vbase0 + k0);
            bf16x8 vb1 = *(const bf16x8*)(vbase1 + k0);
            o0 = __builtin_amdgcn_mfma_f32_16x16x32_bf16(pa, vb0, o0, 0, 0, 0);
            o1 = __builtin_amdgcn_mfma_f32_16x16x32_bf16(pa, vb1, o1, 0, 0, 0);
        }
    }
    __syncthreads();   // all p reads done; obuf may alias p_lds now

    // ---- cross-wave O reduce (8 partials): 256 threads x 2 packed elements
#pragma unroll
    for (int j = 0; j < 4; j++) {
        obuf[w * 512 + (lg * 4 + j) * 32 + lq]      = o0[j];
        obuf[w * 512 + (lg * 4 + j) * 32 + 16 + lq] = o1[j];
    }
    __syncthreads();
    if (t < 256) {
        int e0 = t * 2;                        // 0..510, covers all 512 outputs
        int q = e0 >> 5, d = e0 & 31;
        f32x2 s = *(const f32x2*)&obuf[e0];
#pragma unroll
        for (int ww = 1; ww < 8; ww++) s += *(const f32x2*)&obuf[ww * 512 + e0];
        unsigned uo;
        asm("v_cvt_pk_bf16_f32 %0, %1, %2" : "=v"(uo) : "v"(s.x), "v"(s.y));
        *(unsigned*)(O + ((size_t)(c * SQL + qbase + q)) * DIM + h * HDIM + d) = uo;
    }
}

// ---------------------------------------------------------------- driver

extern "C" void kernel_launch(void* const* d_in, const int* in_sizes, int n_in,
                              void* d_out, int out_size, void* d_ws, size_t ws_size,
                              hipStream_t stream) {
    const float* pose = (const float*)d_in[0];
    const float* vel  = (const float*)d_in[1];
    const float* img  = (const float*)d_in[2];
    const float* Wq   = (const float*)d_in[3];
    const float* bq   = (const float*)d_in[4];
    const float* Wk   = (const float*)d_in[5];
    const float* bk   = (const float*)d_in[6];
    const float* Wv   = (const float*)d_in[7];
    const float* bv   = (const float*)d_in[8];
    const float* Wo   = (const float*)d_in[9];
    const float* bo   = (const float*)d_in[10];
    const float* an_g = (const float*)d_in[11];
    const float* an_b = (const float*)d_in[12];
    const float* W1   = (const float*)d_in[13];
    const float* b1   = (const float*)d_in[14];
    const float* W2   = (const float*)d_in[15];
    const float* b2   = (const float*)d_in[16];
    const float* fn_g = (const float*)d_in[17];
    const float* fn_b = (const float*)d_in[18];
    const float* n_g  = (const float*)d_in[19];
    const float* n_b  = (const float*)d_in[20];

    const size_t SZ = (size_t)ROWS * DIM;           // 1M elements
    float* X    = (float*)d_ws;                     // fp32 residual stream
    short* Xb   = (short*)(X + SZ);
    short* KVb  = Xb + SZ;
    short* T1b  = KVb + SZ;                         // attn out bf16
    short* Kb4  = T1b + SZ;                         // [L][4096][256] bf16
    short* Vt4  = Kb4 + (size_t)NL * SZ;            // [L][CB][DIM][SKL] bf16
    short* Wqt  = Vt4 + (size_t)NL * SZ;
    short* Wkt  = Wqt + (size_t)NL * DIM * DIM;
    short* Wvt  = Wkt + (size_t)NL * DIM * DIM;
    short* Wot  = Wvt + (size_t)NL * DIM * DIM;
    short* W1t  = Wot + (size_t)NL * DIM * DIM;     // [L][768][256]
    short* W2t  = W1t + (size_t)NL * DIM * FFD;     // [L][256][768]

    {
        int total = CB * SQL * DIM;
        init_kernel<<<(total + 255) / 256, 256, 0, stream>>>(pose, vel, img, X, Xb, KVb);
    }
    transpose_all<<<640, 256, 0, stream>>>(Wq, Wk, Wv, Wo, W1, W2,
                                           Wqt, Wkt, Wvt, Wot, W1t, W2t);
    kv_gemm<<<dim3(DIM / 64, ROWS / 64, 2 * NL), 256, 0, stream>>>(
        KVb, Wkt, Wvt, bk, bv, Kb4, Vt4);

    const float qscale = 0.08838834764831845f;      // 0.5 / sqrt(32)

    for (int i = 0; i < NL; i++) {
        const short* Wqt_i = Wqt + (size_t)i * DIM * DIM;
        const short* Wot_i = Wot + (size_t)i * DIM * DIM;
        const short* W1t_i = W1t + (size_t)i * DIM * FFD;
        const short* W2t_i = W2t + (size_t)i * DIM * FFD;

        attn_mfma<<<2048, 512, 0, stream>>>(
            Xb, Wqt_i, bq + i * DIM, Kb4 + (size_t)i * SZ, Vt4 + (size_t)i * SZ,
            T1b, qscale);

        float* outp  = (i == NL - 1) ? (float*)d_out : X;
        short* outbp = (i == NL - 1) ? nullptr : Xb;
        fused_tail<<<ROWS / 16, 512, 0, stream>>>(
            T1b, Wot_i, bo + i * DIM, X,
            an_g + i * DIM, an_b + i * DIM, fn_g + i * DIM, fn_b + i * DIM,
            W1t_i, b1 + i * FFD, W2t_i, b2 + i * DIM,
            n_g + i * DIM, n_b + i * DIM, outp, outbp);
    }

    (void)in_sizes; (void)n_in; (void)out_size; (void)ws_size;
}

// Round 18
// 384.963 us; speedup vs baseline: 1.2341x; 1.0247x over previous
//
#include <hip/hip_runtime.h>
#include <math.h>

#define NL   4
#define DIM  256
#define NH   8
#define HDIM 32
#define SQL  1024
#define SKL  1024
#define FFD  768
#define CB   4              // combined batch: 2 stacks * 2 batch
#define ROWS (CB * SQL)     // 4096

typedef __attribute__((ext_vector_type(8))) short bf16x8;
typedef __attribute__((ext_vector_type(4))) short bf16x4;
typedef __attribute__((ext_vector_type(4))) float f32x4;
typedef __attribute__((ext_vector_type(2))) float f32x2;

// ---------------------------------------------------------------- utilities

__device__ __forceinline__ short f2bf(float f) {
    union { float f; unsigned u; } v; v.f = f;
    unsigned u = v.u + 0x7fffu + ((v.u >> 16) & 1u);   // RNE
    return (short)(u >> 16);
}

// mish(x) = x*tanh(softplus(x)) = x*(u^2+2u)/(u^2+2u+2), u = e^x.
__device__ __forceinline__ float fast_mish(float x) {
    float u = __expf(fminf(x, 20.0f));
    float a = __builtin_fmaf(u, u, 2.0f * u);          // u^2 + 2u
    return x * a * __builtin_amdgcn_rcpf(a + 2.0f);
}

__device__ __forceinline__ f32x2 lo2(f32x4 v) { return __builtin_shufflevector(v, v, 0, 1); }
__device__ __forceinline__ f32x2 hi2(f32x4 v) { return __builtin_shufflevector(v, v, 2, 3); }

// ---------------------------------------------------------------- init

__global__ __launch_bounds__(256) void init_kernel(
        const float* __restrict__ pose, const float* __restrict__ vel,
        const float* __restrict__ img, float* __restrict__ X,
        short* __restrict__ Xb, short* __restrict__ KVb) {
    int idx = blockIdx.x * 256 + threadIdx.x;
    if (idx >= CB * SQL * DIM) return;
    int c = idx / (SQL * DIM);
    int rem = idx - c * (SQL * DIM);
    int b = c & 1;
    float pv = pose[b * SQL * DIM + rem];
    X[idx]  = pv;
    Xb[idx] = f2bf(pv);
    const float* kv = (c < 2) ? vel : img;
    KVb[idx] = f2bf(kv[b * SQL * DIM + rem]);
}

// ---------------------------------------------------------------- merged weight transpose
// 640 blocks: z<256 QKVO (4 mats x 4 layers x 16 tiles), z<448 W1, else W2.

__global__ __launch_bounds__(256) void transpose_all(
        const float* __restrict__ Wq, const float* __restrict__ Wk,
        const float* __restrict__ Wv, const float* __restrict__ Wo,
        const float* __restrict__ W1, const float* __restrict__ W2,
        short* __restrict__ Wqt, short* __restrict__ Wkt,
        short* __restrict__ Wvt, short* __restrict__ Wot,
        short* __restrict__ W1t, short* __restrict__ W2t) {
    __shared__ float tile[64][65];
    int z = blockIdx.x;
    const float* src; short* dst; int K, N, tx, ty;
    if (z < 256) {
        int m = z >> 6, lyr = (z >> 4) & 3, r = z & 15;
        src = ((m == 0) ? Wq : (m == 1) ? Wk : (m == 2) ? Wv : Wo) + (size_t)lyr * DIM * DIM;
        dst = ((m == 0) ? Wqt : (m == 1) ? Wkt : (m == 2) ? Wvt : Wot) + (size_t)lyr * DIM * DIM;
        K = DIM; N = DIM; tx = r & 3; ty = r >> 2;
    } else if (z < 448) {
        int idx = z - 256, lyr = idx / 48, r = idx % 48;
        src = W1 + (size_t)lyr * DIM * FFD; dst = W1t + (size_t)lyr * DIM * FFD;
        K = DIM; N = FFD; tx = r % 12; ty = r / 12;
    } else {
        int idx = z - 448, lyr = idx / 48, r = idx % 48;
        src = W2 + (size_t)lyr * FFD * DIM; dst = W2t + (size_t)lyr * FFD * DIM;
        K = FFD; N = DIM; tx = r % 4; ty = r / 4;
    }
    int t = threadIdx.x;
    int n0 = tx * 64, k0 = ty * 64;
#pragma unroll
    for (int i = 0; i < 16; i++) {
        int idx = t + i * 256;
        int r = idx >> 6, c = idx & 63;
        tile[r][c] = src[(size_t)(k0 + r) * N + n0 + c];
    }
    __syncthreads();
#pragma unroll
    for (int i = 0; i < 16; i++) {
        int idx = t + i * 256;
        int r = idx >> 6, c = idx & 63;
        dst[(size_t)(n0 + r) * K + k0 + c] = f2bf(tile[c][r]);
    }
}

// ---------------------------------------------------------------- upfront K/V batch
// All 4 layers' K and V projections (input KVb is layer-invariant).
// grid (DIM/64, ROWS/64, 8): z = lyr*2 + {0:K, 1:V}.

__global__ __launch_bounds__(256) void kv_gemm(
        const short* __restrict__ KVb, const short* __restrict__ Wkt,
        const short* __restrict__ Wvt, const float* __restrict__ bk,
        const float* __restrict__ bv, short* __restrict__ Kb4,
        short* __restrict__ Vt4) {
    int z = blockIdx.z, lyr = z >> 1, kv = z & 1;
    const short* Wt   = (kv ? Wvt : Wkt) + (size_t)lyr * DIM * DIM;
    const float* bias = (kv ? bv : bk) + (size_t)lyr * DIM;

    int t = threadIdx.x, l = t & 63, w = t >> 6;
    int lq = l & 15, lg = l >> 4;
    int bm = blockIdx.y * 64, bn = blockIdx.x * 64;

    const short* ap = KVb + (size_t)(bm + w * 16 + lq) * DIM + lg * 8;
    const short* wp = Wt + (size_t)(bn + lq) * DIM + lg * 8;

    f32x4 acc[4];
#pragma unroll
    for (int nt = 0; nt < 4; nt++) acc[nt] = (f32x4){0.f, 0.f, 0.f, 0.f};
#pragma unroll
    for (int k0 = 0; k0 < DIM; k0 += 32) {
        bf16x8 af = *(const bf16x8*)(ap + k0);
#pragma unroll
        for (int nt = 0; nt < 4; nt++) {
            bf16x8 bfr = *(const bf16x8*)(wp + (size_t)nt * 16 * DIM + k0);
            acc[nt] = __builtin_amdgcn_mfma_f32_16x16x32_bf16(af, bfr, acc[nt], 0, 0, 0);
        }
    }

    int ms = bm + w * 16 + lg * 4;
#pragma unroll
    for (int nt = 0; nt < 4; nt++) {
        int col = bn + nt * 16 + lq;
        float bv_ = bias[col];
        if (kv == 0) {
            short* out = Kb4 + (size_t)lyr * ROWS * DIM;
#pragma unroll
            for (int j = 0; j < 4; j++)
                out[(size_t)(ms + j) * DIM + col] = f2bf(acc[nt][j] + bv_);
        } else {
            int cc = ms >> 10, kl = ms & 1023;
            bf16x4 pk;
#pragma unroll
            for (int j = 0; j < 4; j++) pk[j] = f2bf(acc[nt][j] + bv_);
            *(bf16x4*)(Vt4 + (size_t)lyr * ROWS * DIM + ((size_t)(cc * DIM + col)) * SKL + kl) = pk;
        }
    }
}

// ---------------------------------------------------------------- fused tail (1024 thr)
// 16 waves = 4 waves/SIMD for latency hiding; 16-row tiles, grid ROWS/16.
// G = T1b@Wo + bo; x1 = X + LN(G)*ag+ab; y = LN(x1)*fg+fb;
// g1 = mish(y@W1+b1); x2 = g1@W2 + b2 + x1; out = X + LN(x2)*g+b.

__global__ __launch_bounds__(1024) void fused_tail(
        const short* __restrict__ T1b, const short* __restrict__ Wot,
        const float* __restrict__ bo, const float* __restrict__ Xres,
        const float* __restrict__ ag, const float* __restrict__ ab,
        const float* __restrict__ fg, const float* __restrict__ fb,
        const short* __restrict__ W1t, const float* __restrict__ b1,
        const short* __restrict__ W2t, const float* __restrict__ b2,
        const float* __restrict__ g_, const float* __restrict__ b_,
        float* __restrict__ outf, short* __restrict__ outb) {
    __shared__ float gbuf[16][264];                     // G, then x1 (kept to phase E)
    __shared__ __align__(16) short y_lds[16][280];      // y bf16
    __shared__ __align__(16) short g1[16][792];         // mish out bf16
    float (*xbuf)[264] = (float(*)[264])g1;             // x2 fp32, aliases g1 after phase D

    int t = threadIdx.x, l = t & 63, w = t >> 6;        // w: 0..15
    int lq = l & 15, lg = l >> 4;
    int bm = blockIdx.x * 16;

    // ---- phase A: out-proj, wave w -> cols [16w, 16w+16)
    {
        const short* ap = T1b + (size_t)(bm + lq) * DIM + lg * 8;
        const short* wp = Wot + (size_t)(w * 16 + lq) * DIM + lg * 8;
        f32x4 acc = (f32x4){0.f, 0.f, 0.f, 0.f};
#pragma unroll
        for (int k0 = 0; k0 < DIM; k0 += 32) {
            bf16x8 af = *(const bf16x8*)(ap + k0);
            bf16x8 bfr = *(const bf16x8*)(wp + k0);
            acc = __builtin_amdgcn_mfma_f32_16x16x32_bf16(af, bfr, acc, 0, 0, 0);
        }
        int col = w * 16 + lq;
        float bv_ = bo[col];
#pragma unroll
        for (int j = 0; j < 4; j++) gbuf[lg * 4 + j][col] = acc[j] + bv_;
    }
    __syncthreads();

    // ---- phase B: LN(G)+res -> x1 (in-place in gbuf); LN(x1) -> y_lds bf16
    {
        int g = t >> 6, u = t & 63;                     // 16 rows x 64 lanes, 4 elems
        int row = bm + g;
        float s = 0.f, s2 = 0.f;
#pragma unroll
        for (int i = 0; i < 4; i++) {
            float v = gbuf[g][u + 64 * i];
            s += v; s2 += v * v;
        }
#pragma unroll
        for (int off = 1; off < 64; off <<= 1) { s += __shfl_xor(s, off); s2 += __shfl_xor(s2, off); }
        float m = s * (1.f / DIM);
        float rstd = rsqrtf(s2 * (1.f / DIM) - m * m + 1e-5f);

        float x1v[4];
        float sb = 0.f, sb2 = 0.f;
#pragma unroll
        for (int i = 0; i < 4; i++) {
            int col = u + 64 * i;
            float x1 = Xres[(size_t)row * DIM + col] + (gbuf[g][col] - m) * rstd * ag[col] + ab[col];
            x1v[i] = x1; sb += x1; sb2 += x1 * x1;
        }
#pragma unroll
        for (int off = 1; off < 64; off <<= 1) { sb += __shfl_xor(sb, off); sb2 += __shfl_xor(sb2, off); }
        float m2 = sb * (1.f / DIM);
        float rstd2 = rsqrtf(sb2 * (1.f / DIM) - m2 * m2 + 1e-5f);
#pragma unroll
        for (int i = 0; i < 4; i++) {
            int col = u + 64 * i;
            gbuf[g][col]  = x1v[i];                                   // keep x1
            y_lds[g][col] = f2bf((x1v[i] - m2) * rstd2 * fg[col] + fb[col]);
        }
    }
    __syncthreads();

    // ---- phase C: g1 = mish(y@W1+b1); wave w -> cols [48w, 48w+48)
    {
        const short* wp = W1t + (size_t)(w * 48 + lq) * DIM + lg * 8;
        f32x4 acc[3];
#pragma unroll
        for (int nt = 0; nt < 3; nt++) acc[nt] = (f32x4){0.f, 0.f, 0.f, 0.f};
#pragma unroll
        for (int k0 = 0; k0 < DIM; k0 += 32) {
            bf16x8 af = *(const bf16x8*)(&y_lds[lq][k0 + lg * 8]);
#pragma unroll
            for (int nt = 0; nt < 3; nt++) {
                bf16x8 bfr = *(const bf16x8*)(wp + (size_t)nt * 16 * DIM + k0);
                acc[nt] = __builtin_amdgcn_mfma_f32_16x16x32_bf16(af, bfr, acc[nt], 0, 0, 0);
            }
        }
#pragma unroll
        for (int nt = 0; nt < 3; nt++) {
            int col = w * 48 + nt * 16 + lq;
            float bv_ = b1[col];
#pragma unroll
            for (int j = 0; j < 4; j++)
                g1[lg * 4 + j][col] = f2bf(fast_mish(acc[nt][j] + bv_));
        }
    }
    __syncthreads();

    // ---- phase D: x2 = g1@W2 + b2 + x1; wave w -> cols [16w, 16w+16), K=768
    f32x4 acc2 = (f32x4){0.f, 0.f, 0.f, 0.f};
    {
        const short* wp2 = W2t + (size_t)(w * 16 + lq) * FFD + lg * 8;
#pragma unroll 6
        for (int ks = 0; ks < 24; ks++) {
            bf16x8 af = *(const bf16x8*)(&g1[lq][ks * 32 + lg * 8]);
            bf16x8 bfr = *(const bf16x8*)(wp2 + ks * 32);
            acc2 = __builtin_amdgcn_mfma_f32_16x16x32_bf16(af, bfr, acc2, 0, 0, 0);
        }
    }
    __syncthreads();   // all g1 reads done; xbuf may alias now
    {
        int col = w * 16 + lq;
        float bv_ = b2[col];
#pragma unroll
        for (int j = 0; j < 4; j++)
            xbuf[lg * 4 + j][col] = acc2[j] + bv_ + gbuf[lg * 4 + j][col];
    }
    __syncthreads();

    // ---- phase E: out = X + LN(x2)*g+b
    {
        int g = t >> 6, u = t & 63;
        int row = bm + g;
        float s = 0.f, s2 = 0.f;
#pragma unroll
        for (int i = 0; i < 4; i++) {
            float v = xbuf[g][u + 64 * i];
            s += v; s2 += v * v;
        }
#pragma unroll
        for (int off = 1; off < 64; off <<= 1) { s += __shfl_xor(s, off); s2 += __shfl_xor(s2, off); }
        float m = s * (1.f / DIM);
        float rstd = rsqrtf(s2 * (1.f / DIM) - m * m + 1e-5f);
#pragma unroll
        for (int i = 0; i < 4; i++) {
            int col = u + 64 * i;
            float o = Xres[(size_t)row * DIM + col] + (xbuf[g][col] - m) * rstd * g_[col] + b_[col];
            outf[(size_t)row * DIM + col] = o;
            if (outb) outb[(size_t)row * DIM + col] = f2bf(o);
        }
    }
}

// ---------------------------------------------------------------- attention
// (exact r13 structure) 512 thr = 8 waves; wave w owns k in [128w, 128w+128).
// Q computed in-kernel. Entmax: round 1 = full-support plain sums (no row-max),
// then DYNAMIC clipped Michelot rounds with early exit (cap 8).
// p_lds [8][16][128] swizzled; obuf aliases p_lds.

__global__ __launch_bounds__(512, 6) void attn_mfma(
        const short* __restrict__ Xb, const short* __restrict__ Wqt,
        const float* __restrict__ bq, const short* __restrict__ K,
        const short* __restrict__ Vt, short* __restrict__ O, float qscale) {
    int id = blockIdx.x;
    int xcd = id & 7, rest = id >> 3;          // rest: 0..255
    int hc = xcd * 4 + (rest >> 6);            // 0..31, bijective
    int c = hc & 3, h = hc >> 2;
    int qbase = (rest & 63) * 16;
    int t = threadIdx.x, l = t & 63, w = t >> 6;   // w: 0..7
    int lq = l & 15, lg = l >> 4;

    __shared__ __align__(16) short p_lds[8][16 * 128]; // 32KB; [wave][q][k] swizzled
    __shared__ __align__(16) short q_lds[16][40];      // Q tile bf16, padded rows
    __shared__ float sred[2][3][8][16];                // [buf][qty][wave][q]
    float* obuf = (float*)p_lds;                       // [8][512], aliased after PV

    // ---- Q mini-GEMM: waves 0,1 compute d-range [16w, 16w+16) of this head
    if (w < 2) {
        const short* ap = Xb + (size_t)(c * SQL + qbase + lq) * DIM + lg * 8;
        const short* wp = Wqt + (size_t)(h * HDIM + w * 16 + lq) * DIM + lg * 8;
        f32x4 qa = {0.f, 0.f, 0.f, 0.f};
#pragma unroll
        for (int k0 = 0; k0 < DIM; k0 += 32) {
            bf16x8 af = *(const bf16x8*)(ap + k0);
            bf16x8 bfr = *(const bf16x8*)(wp + k0);
            qa = __builtin_amdgcn_mfma_f32_16x16x32_bf16(af, bfr, qa, 0, 0, 0);
        }
        float bb = bq[h * HDIM + w * 16 + lq];
#pragma unroll
        for (int j = 0; j < 4; j++)
            q_lds[lg * 4 + j][w * 16 + lq] = f2bf((qa[j] + bb) * qscale);
    }
    __syncthreads();
    bf16x8 qfrag = *(const bf16x8*)&q_lds[lq][lg * 8];

    // ---- QK^T: acc[kt][j] = S[k = 128w+16kt+4lg+j][q=lq]
    const int kw = w * 128;
    f32x4 acc[8];
#pragma unroll
    for (int kt = 0; kt < 8; kt++) {
        bf16x8 kf = *(const bf16x8*)(K + ((size_t)(c * SKL + kw + kt * 16 + lq)) * DIM + h * HDIM + lg * 8);
        f32x4 z = {0.f, 0.f, 0.f, 0.f};
        acc[kt] = __builtin_amdgcn_mfma_f32_16x16x32_bf16(kf, qfrag, z, 0, 0, 0);
    }

    const f32x2 z2  = {0.f, 0.f};
    const f32x2 big = {1e30f, 1e30f};
    const f32x2 one = {1.f, 1.f};
    float tau;

    // ---- round 1: full support, plain sums (no clipping, no max)
    {
        f32x2 S1 = z2, S2 = z2;
#pragma unroll
        for (int kt = 0; kt < 8; kt++) {
            f32x2 x0 = lo2(acc[kt]), x1 = hi2(acc[kt]);
            S1 += x0; S1 += x1;
            S2 += x0 * x0; S2 += x1 * x1;
        }
        float sy = S1.x + S1.y, sy2 = S2.x + S2.y;
        sy  += __shfl_xor(sy, 16);  sy  += __shfl_xor(sy, 32);
        sy2 += __shfl_xor(sy2, 16); sy2 += __shfl_xor(sy2, 32);
        if (l < 16) { sred[0][0][w][l] = sy; sred[0][1][w][l] = sy2; }
        __syncthreads();
        sy = sred[0][0][0][lq]; sy2 = sred[0][1][0][lq];
#pragma unroll
        for (int ww = 1; ww < 8; ww++) {
            sy  += sred[0][0][ww][lq];
            sy2 += sred[0][1][ww][lq];
        }
        const float N = (float)SKL;
        float disc = fmaxf(sy * sy - N * (sy2 - 1.0f), 0.f);
        tau = (sy - sqrtf(disc)) * (1.0f / N);
    }

    // ---- dynamic clipped Michelot rounds, early exit, cap 8
    int r = 0;
    for (;;) {
        int b = 1 - (r & 1);                   // buffers 1,0,1,0,... (round 1 used 0)
        f32x2 vt = {tau, tau};
        f32x2 S1 = z2, S2 = z2, NN = z2;
#pragma unroll
        for (int kt = 0; kt < 8; kt++) {
            f32x2 y0 = __builtin_elementwise_max(lo2(acc[kt]) - vt, z2);
            f32x2 y1 = __builtin_elementwise_max(hi2(acc[kt]) - vt, z2);
            S1 += y0; S1 += y1;
            S2 += y0 * y0; S2 += y1 * y1;
            NN += __builtin_elementwise_min(y0 * big, one);
            NN += __builtin_elementwise_min(y1 * big, one);
        }
        float sy = S1.x + S1.y, sy2 = S2.x + S2.y, nn = NN.x + NN.y;
        sy  += __shfl_xor(sy, 16);  sy  += __shfl_xor(sy, 32);
        sy2 += __shfl_xor(sy2, 16); sy2 += __shfl_xor(sy2, 32);
        nn  += __shfl_xor(nn, 16);  nn  += __shfl_xor(nn, 32);
        if (l < 16) { sred[b][0][w][l] = nn; sred[b][1][w][l] = sy; sred[b][2][w][l] = sy2; }
        __syncthreads();
        nn = sred[b][0][0][lq]; sy = sred[b][1][0][lq]; sy2 = sred[b][2][0][lq];
#pragma unroll
        for (int ww = 1; ww < 8; ww++) {
            nn  += sred[b][0][ww][lq];
            sy  += sred[b][1][ww][lq];
            sy2 += sred[b][2][ww][lq];
        }
        float disc = fmaxf(sy * sy - nn * (sy2 - 1.0f), 0.f);
        float delta = (sy - sqrtf(disc)) / nn;
        tau += delta;
        r++;
        if (r >= 8 || __all(delta < 1e-6f)) break;
    }

    // ---- p -> wave-private swizzled LDS (all 128 k), then PV
    f32x4 o0 = {0.f, 0.f, 0.f, 0.f}, o1 = {0.f, 0.f, 0.f, 0.f};
    const short* vbase0 = Vt + ((size_t)(c * DIM + h * HDIM + lq)) * SKL;
    const short* vbase1 = vbase0 + (size_t)16 * SKL;
    {
        f32x2 vt = {tau, tau};
        int swz = lq << 4;
#pragma unroll
        for (int kt = 0; kt < 8; kt++) {
            f32x2 y0 = __builtin_elementwise_max(lo2(acc[kt]) - vt, z2);
            f32x2 y1 = __builtin_elementwise_max(hi2(acc[kt]) - vt, z2);
            f32x2 p0 = y0 * y0, p1 = y1 * y1;
            unsigned u01, u23;
            asm("v_cvt_pk_bf16_f32 %0, %1, %2" : "=v"(u01) : "v"(p0.x), "v"(p0.y));
            asm("v_cvt_pk_bf16_f32 %0, %1, %2" : "=v"(u23) : "v"(p1.x), "v"(p1.y));
            int byte = lq * 256 + ((kt * 32 + lg * 8) ^ swz);
            *(uint2*)((char*)p_lds[w] + byte) = make_uint2(u01, u23);
        }
#pragma unroll
        for (int k2 = 0; k2 < 4; k2++) {
            int byte = lq * 256 + ((k2 * 64 + lg * 16) ^ swz);
            bf16x8 pa = *(const bf16x8*)((const char*)p_lds[w] + byte);
            int k0 = kw + k2 * 32 + lg * 8;
            bf16x8 vb0 = *(const bf16x8*)(vbase0 + k0);
            bf16x8 vb1 = *(const bf16x8*)(vbase1 + k0);
            o0 = __builtin_amdgcn_mfma_f32_16x16x32_bf16(pa, vb0, o0, 0, 0, 0);
            o1 = __builtin_amdgcn_mfma_f32_16x16x32_bf16(pa, vb1, o1, 0, 0, 0);
        }
    }
    __syncthreads();   // all p reads done; obuf may alias p_lds now

    // ---- cross-wave O reduce (8 partials): 256 threads x 2 packed elements
#pragma unroll
    for (int j = 0; j < 4; j++) {
        obuf[w * 512 + (lg * 4 + j) * 32 + lq]      = o0[j];
        obuf[w * 512 + (lg * 4 + j) * 32 + 16 + lq] = o1[j];
    }
    __syncthreads();
    if (t < 256) {
        int e0 = t * 2;                        // 0..510, covers all 512 outputs
        int q = e0 >> 5, d = e0 & 31;
        f32x2 s = *(const f32x2*)&obuf[e0];
#pragma unroll
        for (int ww = 1; ww < 8; ww++) s += *(const f32x2*)&obuf[ww * 512 + e0];
        unsigned uo;
        asm("v_cvt_pk_bf16_f32 %0, %1, %2" : "=v"(uo) : "v"(s.x), "v"(s.y));
        *(unsigned*)(O + ((size_t)(c * SQL + qbase + q)) * DIM + h * HDIM + d) = uo;
    }
}

// ---------------------------------------------------------------- driver

extern "C" void kernel_launch(void* const* d_in, const int* in_sizes, int n_in,
                              void* d_out, int out_size, void* d_ws, size_t ws_size,
                              hipStream_t stream) {
    const float* pose = (const float*)d_in[0];
    const float* vel  = (const float*)d_in[1];
    const float* img  = (const float*)d_in[2];
    const float* Wq   = (const float*)d_in[3];
    const float* bq   = (const float*)d_in[4];
    const float* Wk   = (const float*)d_in[5];
    const float* bk   = (const float*)d_in[6];
    const float* Wv   = (const float*)d_in[7];
    const float* bv   = (const float*)d_in[8];
    const float* Wo   = (const float*)d_in[9];
    const float* bo   = (const float*)d_in[10];
    const float* an_g = (const float*)d_in[11];
    const float* an_b = (const float*)d_in[12];
    const float* W1   = (const float*)d_in[13];
    const float* b1   = (const float*)d_in[14];
    const float* W2   = (const float*)d_in[15];
    const float* b2   = (const float*)d_in[16];
    const float* fn_g = (const float*)d_in[17];
    const float* fn_b = (const float*)d_in[18];
    const float* n_g  = (const float*)d_in[19];
    const float* n_b  = (const float*)d_in[20];

    const size_t SZ = (size_t)ROWS * DIM;           // 1M elements
    float* X    = (float*)d_ws;                     // fp32 residual stream
    short* Xb   = (short*)(X + SZ);
    short* KVb  = Xb + SZ;
    short* T1b  = KVb + SZ;                         // attn out bf16
    short* Kb4  = T1b + SZ;                         // [L][4096][256] bf16
    short* Vt4  = Kb4 + (size_t)NL * SZ;            // [L][CB][DIM][SKL] bf16
    short* Wqt  = Vt4 + (size_t)NL * SZ;
    short* Wkt  = Wqt + (size_t)NL * DIM * DIM;
    short* Wvt  = Wkt + (size_t)NL * DIM * DIM;
    short* Wot  = Wvt + (size_t)NL * DIM * DIM;
    short* W1t  = Wot + (size_t)NL * DIM * DIM;     // [L][768][256]
    short* W2t  = W1t + (size_t)NL * DIM * FFD;     // [L][256][768]

    {
        int total = CB * SQL * DIM;
        init_kernel<<<(total + 255) / 256, 256, 0, stream>>>(pose, vel, img, X, Xb, KVb);
    }
    transpose_all<<<640, 256, 0, stream>>>(Wq, Wk, Wv, Wo, W1, W2,
                                           Wqt, Wkt, Wvt, Wot, W1t, W2t);
    kv_gemm<<<dim3(DIM / 64, ROWS / 64, 2 * NL), 256, 0, stream>>>(
        KVb, Wkt, Wvt, bk, bv, Kb4, Vt4);

    const float qscale = 0.08838834764831845f;      // 0.5 / sqrt(32)

    for (int i = 0; i < NL; i++) {
        const short* Wqt_i = Wqt + (size_t)i * DIM * DIM;
        const short* Wot_i = Wot + (size_t)i * DIM * DIM;
        const short* W1t_i = W1t + (size_t)i * DIM * FFD;
        const short* W2t_i = W2t + (size_t)i * DIM * FFD;

        attn_mfma<<<2048, 512, 0, stream>>>(
            Xb, Wqt_i, bq + i * DIM, Kb4 + (size_t)i * SZ, Vt4 + (size_t)i * SZ,
            T1b, qscale);

        float* outp  = (i == NL - 1) ? (float*)d_out : X;
        short* outbp = (i == NL - 1) ? nullptr : Xb;
        fused_tail<<<ROWS / 16, 1024, 0, stream>>>(
            T1b, Wot_i, bo + i * DIM, X,
            an_g + i * DIM, an_b + i * DIM, fn_g + i * DIM, fn_b + i * DIM,
            W1t_i, b1 + i * FFD, W2t_i, b2 + i * DIM,
            n_g + i * DIM, n_b + i * DIM, outp, outbp);
    }

    (void)in_sizes; (void)n_in; (void)out_size; (void)ws_size;
}

// Round 20
// 384.755 us; speedup vs baseline: 1.2347x; 1.0005x over previous
//
#include <hip/hip_runtime.h>
#include <math.h>

#define NL   4
#define DIM  256
#define NH   8
#define HDIM 32
#define SQL  1024
#define SKL  1024
#define FFD  768
#define CB   4              // combined batch: 2 stacks * 2 batch
#define ROWS (CB * SQL)     // 4096

typedef __attribute__((ext_vector_type(8))) short bf16x8;
typedef __attribute__((ext_vector_type(4))) short bf16x4;
typedef __attribute__((ext_vector_type(4))) float f32x4;
typedef __attribute__((ext_vector_type(2))) float f32x2;

// ---------------------------------------------------------------- utilities

__device__ __forceinline__ short f2bf(float f) {
    union { float f; unsigned u; } v; v.f = f;
    unsigned u = v.u + 0x7fffu + ((v.u >> 16) & 1u);   // RNE
    return (short)(u >> 16);
}

// mish(x) = x*tanh(softplus(x)) = x*(u^2+2u)/(u^2+2u+2), u = e^x.
__device__ __forceinline__ float fast_mish(float x) {
    float u = __expf(fminf(x, 20.0f));
    float a = __builtin_fmaf(u, u, 2.0f * u);          // u^2 + 2u
    return x * a * __builtin_amdgcn_rcpf(a + 2.0f);
}

__device__ __forceinline__ f32x2 lo2(f32x4 v) { return __builtin_shufflevector(v, v, 0, 1); }
__device__ __forceinline__ f32x2 hi2(f32x4 v) { return __builtin_shufflevector(v, v, 2, 3); }

// ---------------------------------------------------------------- init

__global__ __launch_bounds__(256) void init_kernel(
        const float* __restrict__ pose, const float* __restrict__ vel,
        const float* __restrict__ img, float* __restrict__ X,
        short* __restrict__ Xb, short* __restrict__ KVb) {
    int idx = blockIdx.x * 256 + threadIdx.x;
    if (idx >= CB * SQL * DIM) return;
    int c = idx / (SQL * DIM);
    int rem = idx - c * (SQL * DIM);
    int b = c & 1;
    float pv = pose[b * SQL * DIM + rem];
    X[idx]  = pv;
    Xb[idx] = f2bf(pv);
    const float* kv = (c < 2) ? vel : img;
    KVb[idx] = f2bf(kv[b * SQL * DIM + rem]);
}

// ---------------------------------------------------------------- merged weight transpose
// 640 blocks: z<256 QKVO (4 mats x 4 layers x 16 tiles), z<448 W1, else W2.

__global__ __launch_bounds__(256) void transpose_all(
        const float* __restrict__ Wq, const float* __restrict__ Wk,
        const float* __restrict__ Wv, const float* __restrict__ Wo,
        const float* __restrict__ W1, const float* __restrict__ W2,
        short* __restrict__ Wqt, short* __restrict__ Wkt,
        short* __restrict__ Wvt, short* __restrict__ Wot,
        short* __restrict__ W1t, short* __restrict__ W2t) {
    __shared__ float tile[64][65];
    int z = blockIdx.x;
    const float* src; short* dst; int K, N, tx, ty;
    if (z < 256) {
        int m = z >> 6, lyr = (z >> 4) & 3, r = z & 15;
        src = ((m == 0) ? Wq : (m == 1) ? Wk : (m == 2) ? Wv : Wo) + (size_t)lyr * DIM * DIM;
        dst = ((m == 0) ? Wqt : (m == 1) ? Wkt : (m == 2) ? Wvt : Wot) + (size_t)lyr * DIM * DIM;
        K = DIM; N = DIM; tx = r & 3; ty = r >> 2;
    } else if (z < 448) {
        int idx = z - 256, lyr = idx / 48, r = idx % 48;
        src = W1 + (size_t)lyr * DIM * FFD; dst = W1t + (size_t)lyr * DIM * FFD;
        K = DIM; N = FFD; tx = r % 12; ty = r / 12;
    } else {
        int idx = z - 448, lyr = idx / 48, r = idx % 48;
        src = W2 + (size_t)lyr * FFD * DIM; dst = W2t + (size_t)lyr * FFD * DIM;
        K = FFD; N = DIM; tx = r % 4; ty = r / 4;
    }
    int t = threadIdx.x;
    int n0 = tx * 64, k0 = ty * 64;
#pragma unroll
    for (int i = 0; i < 16; i++) {
        int idx = t + i * 256;
        int r = idx >> 6, c = idx & 63;
        tile[r][c] = src[(size_t)(k0 + r) * N + n0 + c];
    }
    __syncthreads();
#pragma unroll
    for (int i = 0; i < 16; i++) {
        int idx = t + i * 256;
        int r = idx >> 6, c = idx & 63;
        dst[(size_t)(n0 + r) * K + k0 + c] = f2bf(tile[c][r]);
    }
}

// ---------------------------------------------------------------- upfront K/V batch
// All 4 layers' K and V projections (input KVb is layer-invariant).
// grid (DIM/64, ROWS/64, 8): z = lyr*2 + {0:K, 1:V}.

__global__ __launch_bounds__(256) void kv_gemm(
        const short* __restrict__ KVb, const short* __restrict__ Wkt,
        const short* __restrict__ Wvt, const float* __restrict__ bk,
        const float* __restrict__ bv, short* __restrict__ Kb4,
        short* __restrict__ Vt4) {
    int z = blockIdx.z, lyr = z >> 1, kv = z & 1;
    const short* Wt   = (kv ? Wvt : Wkt) + (size_t)lyr * DIM * DIM;
    const float* bias = (kv ? bv : bk) + (size_t)lyr * DIM;

    int t = threadIdx.x, l = t & 63, w = t >> 6;
    int lq = l & 15, lg = l >> 4;
    int bm = blockIdx.y * 64, bn = blockIdx.x * 64;

    const short* ap = KVb + (size_t)(bm + w * 16 + lq) * DIM + lg * 8;
    const short* wp = Wt + (size_t)(bn + lq) * DIM + lg * 8;

    f32x4 acc[4];
#pragma unroll
    for (int nt = 0; nt < 4; nt++) acc[nt] = (f32x4){0.f, 0.f, 0.f, 0.f};
#pragma unroll
    for (int k0 = 0; k0 < DIM; k0 += 32) {
        bf16x8 af = *(const bf16x8*)(ap + k0);
#pragma unroll
        for (int nt = 0; nt < 4; nt++) {
            bf16x8 bfr = *(const bf16x8*)(wp + (size_t)nt * 16 * DIM + k0);
            acc[nt] = __builtin_amdgcn_mfma_f32_16x16x32_bf16(af, bfr, acc[nt], 0, 0, 0);
        }
    }

    int ms = bm + w * 16 + lg * 4;
#pragma unroll
    for (int nt = 0; nt < 4; nt++) {
        int col = bn + nt * 16 + lq;
        float bv_ = bias[col];
        if (kv == 0) {
            short* out = Kb4 + (size_t)lyr * ROWS * DIM;
#pragma unroll
            for (int j = 0; j < 4; j++)
                out[(size_t)(ms + j) * DIM + col] = f2bf(acc[nt][j] + bv_);
        } else {
            int cc = ms >> 10, kl = ms & 1023;
            bf16x4 pk;
#pragma unroll
            for (int j = 0; j < 4; j++) pk[j] = f2bf(acc[nt][j] + bv_);
            *(bf16x4*)(Vt4 + (size_t)lyr * ROWS * DIM + ((size_t)(cc * DIM + col)) * SKL + kl) = pk;
        }
    }
}

// ---------------------------------------------------------------- fused tail (1024 thr)
// 16 waves = 4 waves/SIMD for latency hiding; 16-row tiles, grid ROWS/16.
// G = T1b@Wo + bo; x1 = X + LN(G)*ag+ab; y = LN(x1)*fg+fb;
// g1 = mish(y@W1+b1); x2 = g1@W2 + b2 + x1; out = X + LN(x2)*g+b.

__global__ __launch_bounds__(1024) void fused_tail(
        const short* __restrict__ T1b, const short* __restrict__ Wot,
        const float* __restrict__ bo, const float* __restrict__ Xres,
        const float* __restrict__ ag, const float* __restrict__ ab,
        const float* __restrict__ fg, const float* __restrict__ fb,
        const short* __restrict__ W1t, const float* __restrict__ b1,
        const short* __restrict__ W2t, const float* __restrict__ b2,
        const float* __restrict__ g_, const float* __restrict__ b_,
        float* __restrict__ outf, short* __restrict__ outb) {
    __shared__ float gbuf[16][264];                     // G, then x1 (kept to phase E)
    __shared__ __align__(16) short y_lds[16][280];      // y bf16
    __shared__ __align__(16) short g1[16][792];         // mish out bf16
    float (*xbuf)[264] = (float(*)[264])g1;             // x2 fp32, aliases g1 after phase D

    int t = threadIdx.x, l = t & 63, w = t >> 6;        // w: 0..15
    int lq = l & 15, lg = l >> 4;
    int bm = blockIdx.x * 16;

    // ---- phase A: out-proj, wave w -> cols [16w, 16w+16)
    {
        const short* ap = T1b + (size_t)(bm + lq) * DIM + lg * 8;
        const short* wp = Wot + (size_t)(w * 16 + lq) * DIM + lg * 8;
        f32x4 acc = (f32x4){0.f, 0.f, 0.f, 0.f};
#pragma unroll
        for (int k0 = 0; k0 < DIM; k0 += 32) {
            bf16x8 af = *(const bf16x8*)(ap + k0);
            bf16x8 bfr = *(const bf16x8*)(wp + k0);
            acc = __builtin_amdgcn_mfma_f32_16x16x32_bf16(af, bfr, acc, 0, 0, 0);
        }
        int col = w * 16 + lq;
        float bv_ = bo[col];
#pragma unroll
        for (int j = 0; j < 4; j++) gbuf[lg * 4 + j][col] = acc[j] + bv_;
    }
    __syncthreads();

    // ---- phase B: LN(G)+res -> x1 (in-place in gbuf); LN(x1) -> y_lds bf16
    {
        int g = t >> 6, u = t & 63;                     // 16 rows x 64 lanes, 4 elems
        int row = bm + g;
        float s = 0.f, s2 = 0.f;
#pragma unroll
        for (int i = 0; i < 4; i++) {
            float v = gbuf[g][u + 64 * i];
            s += v; s2 += v * v;
        }
#pragma unroll
        for (int off = 1; off < 64; off <<= 1) { s += __shfl_xor(s, off); s2 += __shfl_xor(s2, off); }
        float m = s * (1.f / DIM);
        float rstd = rsqrtf(s2 * (1.f / DIM) - m * m + 1e-5f);

        float x1v[4];
        float sb = 0.f, sb2 = 0.f;
#pragma unroll
        for (int i = 0; i < 4; i++) {
            int col = u + 64 * i;
            float x1 = Xres[(size_t)row * DIM + col] + (gbuf[g][col] - m) * rstd * ag[col] + ab[col];
            x1v[i] = x1; sb += x1; sb2 += x1 * x1;
        }
#pragma unroll
        for (int off = 1; off < 64; off <<= 1) { sb += __shfl_xor(sb, off); sb2 += __shfl_xor(sb2, off); }
        float m2 = sb * (1.f / DIM);
        float rstd2 = rsqrtf(sb2 * (1.f / DIM) - m2 * m2 + 1e-5f);
#pragma unroll
        for (int i = 0; i < 4; i++) {
            int col = u + 64 * i;
            gbuf[g][col]  = x1v[i];                                   // keep x1
            y_lds[g][col] = f2bf((x1v[i] - m2) * rstd2 * fg[col] + fb[col]);
        }
    }
    __syncthreads();

    // ---- phase C: g1 = mish(y@W1+b1); wave w -> cols [48w, 48w+48)
    {
        const short* wp = W1t + (size_t)(w * 48 + lq) * DIM + lg * 8;
        f32x4 acc[3];
#pragma unroll
        for (int nt = 0; nt < 3; nt++) acc[nt] = (f32x4){0.f, 0.f, 0.f, 0.f};
#pragma unroll
        for (int k0 = 0; k0 < DIM; k0 += 32) {
            bf16x8 af = *(const bf16x8*)(&y_lds[lq][k0 + lg * 8]);
#pragma unroll
            for (int nt = 0; nt < 3; nt++) {
                bf16x8 bfr = *(const bf16x8*)(wp + (size_t)nt * 16 * DIM + k0);
                acc[nt] = __builtin_amdgcn_mfma_f32_16x16x32_bf16(af, bfr, acc[nt], 0, 0, 0);
            }
        }
#pragma unroll
        for (int nt = 0; nt < 3; nt++) {
            int col = w * 48 + nt * 16 + lq;
            float bv_ = b1[col];
#pragma unroll
            for (int j = 0; j < 4; j++)
                g1[lg * 4 + j][col] = f2bf(fast_mish(acc[nt][j] + bv_));
        }
    }
    __syncthreads();

    // ---- phase D: x2 = g1@W2 + b2 + x1; wave w -> cols [16w, 16w+16), K=768
    f32x4 acc2 = (f32x4){0.f, 0.f, 0.f, 0.f};
    {
        const short* wp2 = W2t + (size_t)(w * 16 + lq) * FFD + lg * 8;
#pragma unroll 6
        for (int ks = 0; ks < 24; ks++) {
            bf16x8 af = *(const bf16x8*)(&g1[lq][ks * 32 + lg * 8]);
            bf16x8 bfr = *(const bf16x8*)(wp2 + ks * 32);
            acc2 = __builtin_amdgcn_mfma_f32_16x16x32_bf16(af, bfr, acc2, 0, 0, 0);
        }
    }
    __syncthreads();   // all g1 reads done; xbuf may alias now
    {
        int col = w * 16 + lq;
        float bv_ = b2[col];
#pragma unroll
        for (int j = 0; j < 4; j++)
            xbuf[lg * 4 + j][col] = acc2[j] + bv_ + gbuf[lg * 4 + j][col];
    }
    __syncthreads();

    // ---- phase E: out = X + LN(x2)*g+b
    {
        int g = t >> 6, u = t & 63;
        int row = bm + g;
        float s = 0.f, s2 = 0.f;
#pragma unroll
        for (int i = 0; i < 4; i++) {
            float v = xbuf[g][u + 64 * i];
            s += v; s2 += v * v;
        }
#pragma unroll
        for (int off = 1; off < 64; off <<= 1) { s += __shfl_xor(s, off); s2 += __shfl_xor(s2, off); }
        float m = s * (1.f / DIM);
        float rstd = rsqrtf(s2 * (1.f / DIM) - m * m + 1e-5f);
#pragma unroll
        for (int i = 0; i < 4; i++) {
            int col = u + 64 * i;
            float o = Xres[(size_t)row * DIM + col] + (xbuf[g][col] - m) * rstd * g_[col] + b_[col];
            outf[(size_t)row * DIM + col] = o;
            if (outb) outb[(size_t)row * DIM + col] = f2bf(o);
        }
    }
}

// ---------------------------------------------------------------- attention
// 512 thr = 8 waves; wave w owns k in [128w, 128w+128). Q computed in-kernel.
// Entmax: round 1 = full-support plain sums (no row-max), then DYNAMIC
// clipped Michelot rounds with early exit (cap 8).
// p_lds [8][16][128] swizzled; obuf aliases p_lds.

__global__ __launch_bounds__(512, 6) void attn_mfma(
        const short* __restrict__ Xb, const short* __restrict__ Wqt,
        const float* __restrict__ bq, const short* __restrict__ K,
        const short* __restrict__ Vt, short* __restrict__ O, float qscale) {
    int id = blockIdx.x;
    int xcd = id & 7, rest = id >> 3;          // rest: 0..255
    int hc = xcd * 4 + (rest >> 6);            // 0..31, bijective
    int c = hc & 3, h = hc >> 2;
    int qbase = (rest & 63) * 16;
    int t = threadIdx.x, l = t & 63, w = t >> 6;   // w: 0..7
    int lq = l & 15, lg = l >> 4;

    __shared__ __align__(16) short p_lds[8][16 * 128]; // 32KB; [wave][q][k] swizzled
    __shared__ __align__(16) short q_lds[16][40];      // Q tile bf16, padded rows
    __shared__ float sred[2][3][8][16];                // [buf][qty][wave][q]
    float* obuf = (float*)p_lds;                       // [8][512], aliased after PV

    // ---- Q mini-GEMM: waves 0,1 compute d-range [16w, 16w+16) of this head
    if (w < 2) {
        const short* ap = Xb + (size_t)(c * SQL + qbase + lq) * DIM + lg * 8;
        const short* wp = Wqt + (size_t)(h * HDIM + w * 16 + lq) * DIM + lg * 8;
        f32x4 qa = {0.f, 0.f, 0.f, 0.f};
#pragma unroll
        for (int k0 = 0; k0 < DIM; k0 += 32) {
            bf16x8 af = *(const bf16x8*)(ap + k0);
            bf16x8 bfr = *(const bf16x8*)(wp + k0);
            qa = __builtin_amdgcn_mfma_f32_16x16x32_bf16(af, bfr, qa, 0, 0, 0);
        }
        float bb = bq[h * HDIM + w * 16 + lq];
#pragma unroll
        for (int j = 0; j < 4; j++)
            q_lds[lg * 4 + j][w * 16 + lq] = f2bf((qa[j] + bb) * qscale);
    }
    __syncthreads();
    bf16x8 qfrag = *(const bf16x8*)&q_lds[lq][lg * 8];

    // ---- QK^T: acc[kt][j] = S[k = 128w+16kt+4lg+j][q=lq]
    const int kw = w * 128;
    f32x4 acc[8];
#pragma unroll
    for (int kt = 0; kt < 8; kt++) {
        bf16x8 kf = *(const bf16x8*)(K + ((size_t)(c * SKL + kw + kt * 16 + lq)) * DIM + h * HDIM + lg * 8);
        f32x4 z = {0.f, 0.f, 0.f, 0.f};
        acc[kt] = __builtin_amdgcn_mfma_f32_16x16x32_bf16(kf, qfrag, z, 0, 0, 0);
    }

    const f32x2 z2  = {0.f, 0.f};
    const f32x2 big = {1e30f, 1e30f};
    const f32x2 one = {1.f, 1.f};
    float tau;

    // ---- round 1: full support, plain sums (no clipping, no max)
    {
        f32x2 S1 = z2, S2 = z2;
#pragma unroll
        for (int kt = 0; kt < 8; kt++) {
            f32x2 x0 = lo2(acc[kt]), x1 = hi2(acc[kt]);
            S1 += x0; S1 += x1;
            S2 += x0 * x0; S2 += x1 * x1;
        }
        float sy = S1.x + S1.y, sy2 = S2.x + S2.y;
        sy  += __shfl_xor(sy, 16);  sy  += __shfl_xor(sy, 32);
        sy2 += __shfl_xor(sy2, 16); sy2 += __shfl_xor(sy2, 32);
        if (l < 16) { sred[0][0][w][l] = sy; sred[0][1][w][l] = sy2; }
        __syncthreads();
        sy = sred[0][0][0][lq]; sy2 = sred[0][1][0][lq];
#pragma unroll
        for (int ww = 1; ww < 8; ww++) {
            sy  += sred[0][0][ww][lq];
            sy2 += sred[0][1][ww][lq];
        }
        const float N = (float)SKL;
        float disc = fmaxf(sy * sy - N * (sy2 - 1.0f), 0.f);
        tau = (sy - sqrtf(disc)) * (1.0f / N);
    }

    // ---- dynamic clipped Michelot rounds, early exit, cap 8
    int r = 0;
    for (;;) {
        int b = 1 - (r & 1);                   // buffers 1,0,1,0,... (round 1 used 0)
        f32x2 vt = {tau, tau};
        f32x2 S1 = z2, S2 = z2, NN = z2;
#pragma unroll
        for (int kt = 0; kt < 8; kt++) {
            f32x2 y0 = __builtin_elementwise_max(lo2(acc[kt]) - vt, z2);
            f32x2 y1 = __builtin_elementwise_max(hi2(acc[kt]) - vt, z2);
            S1 += y0; S1 += y1;
            S2 += y0 * y0; S2 += y1 * y1;
            NN += __builtin_elementwise_min(y0 * big, one);
            NN += __builtin_elementwise_min(y1 * big, one);
        }
        float sy = S1.x + S1.y, sy2 = S2.x + S2.y, nn = NN.x + NN.y;
        sy  += __shfl_xor(sy, 16);  sy  += __shfl_xor(sy, 32);
        sy2 += __shfl_xor(sy2, 16); sy2 += __shfl_xor(sy2, 32);
        nn  += __shfl_xor(nn, 16);  nn  += __shfl_xor(nn, 32);
        if (l < 16) { sred[b][0][w][l] = nn; sred[b][1][w][l] = sy; sred[b][2][w][l] = sy2; }
        __syncthreads();
        nn = sred[b][0][0][lq]; sy = sred[b][1][0][lq]; sy2 = sred[b][2][0][lq];
#pragma unroll
        for (int ww = 1; ww < 8; ww++) {
            nn  += sred[b][0][ww][lq];
            sy  += sred[b][1][ww][lq];
            sy2 += sred[b][2][ww][lq];
        }
        float disc = fmaxf(sy * sy - nn * (sy2 - 1.0f), 0.f);
        float delta = (sy - sqrtf(disc)) / nn;
        tau += delta;
        r++;
        if (r >= 8 || __all(delta < 1e-6f)) break;
    }

    // ---- p -> wave-private swizzled LDS (all 128 k), then PV
    f32x4 o0 = {0.f, 0.f, 0.f, 0.f}, o1 = {0.f, 0.f, 0.f, 0.f};
    const short* vbase0 = Vt + ((size_t)(c * DIM + h * HDIM + lq)) * SKL;
    const short* vbase1 = vbase0 + (size_t)16 * SKL;
    {
        f32x2 vt = {tau, tau};
        int swz = lq << 4;
#pragma unroll
        for (int kt = 0; kt < 8; kt++) {
            f32x2 y0 = __builtin_elementwise_max(lo2(acc[kt]) - vt, z2);
            f32x2 y1 = __builtin_elementwise_max(hi2(acc[kt]) - vt, z2);
            f32x2 p0 = y0 * y0, p1 = y1 * y1;
            unsigned u01, u23;
            asm("v_cvt_pk_bf16_f32 %0, %1, %2" : "=v"(u01) : "v"(p0.x), "v"(p0.y));
            asm("v_cvt_pk_bf16_f32 %0, %1, %2" : "=v"(u23) : "v"(p1.x), "v"(p1.y));
            int byte = lq * 256 + ((kt * 32 + lg * 8) ^ swz);
            *(uint2*)((char*)p_lds[w] + byte) = make_uint2(u01, u23);
        }
#pragma unroll
        for (int k2 = 0; k2 < 4; k2++) {
            int byte = lq * 256 + ((k2 * 64 + lg * 16) ^ swz);
            bf16x8 pa = *(const bf16x8*)((const char*)p_lds[w] + byte);
            int k0 = kw + k2 * 32 + lg * 8;
            bf16x8 vb0 = *(const bf16x8*)(vbase0 + k0);
            bf16x8 vb1 = *(const bf16x8*)(vbase1 + k0);
            o0 = __builtin_amdgcn_mfma_f32_16x16x32_bf16(pa, vb0, o0, 0, 0, 0);
            o1 = __builtin_amdgcn_mfma_f32_16x16x32_bf16(pa, vb1, o1, 0, 0, 0);
        }
    }
    __syncthreads();   // all p reads done; obuf may alias p_lds now

    // ---- cross-wave O reduce (8 partials): 256 threads x 2 packed elements
#pragma unroll
    for (int j = 0; j < 4; j++) {
        obuf[w * 512 + (lg * 4 + j) * 32 + lq]      = o0[j];
        obuf[w * 512 + (lg * 4 + j) * 32 + 16 + lq] = o1[j];
    }
    __syncthreads();
    if (t < 256) {
        int e0 = t * 2;                        // 0..510, covers all 512 outputs
        int q = e0 >> 5, d = e0 & 31;
        f32x2 s = *(const f32x2*)&obuf[e0];
#pragma unroll
        for (int ww = 1; ww < 8; ww++) s += *(const f32x2*)&obuf[ww * 512 + e0];
        unsigned uo;
        asm("v_cvt_pk_bf16_f32 %0, %1, %2" : "=v"(uo) : "v"(s.x), "v"(s.y));
        *(unsigned*)(O + ((size_t)(c * SQL + qbase + q)) * DIM + h * HDIM + d) = uo;
    }
}

// ---------------------------------------------------------------- driver

extern "C" void kernel_launch(void* const* d_in, const int* in_sizes, int n_in,
                              void* d_out, int out_size, void* d_ws, size_t ws_size,
                              hipStream_t stream) {
    const float* pose = (const float*)d_in[0];
    const float* vel  = (const float*)d_in[1];
    const float* img  = (const float*)d_in[2];
    const float* Wq   = (const float*)d_in[3];
    const float* bq   = (const float*)d_in[4];
    const float* Wk   = (const float*)d_in[5];
    const float* bk   = (const float*)d_in[6];
    const float* Wv   = (const float*)d_in[7];
    const float* bv   = (const float*)d_in[8];
    const float* Wo   = (const float*)d_in[9];
    const float* bo   = (const float*)d_in[10];
    const float* an_g = (const float*)d_in[11];
    const float* an_b = (const float*)d_in[12];
    const float* W1   = (const float*)d_in[13];
    const float* b1   = (const float*)d_in[14];
    const float* W2   = (const float*)d_in[15];
    const float* b2   = (const float*)d_in[16];
    const float* fn_g = (const float*)d_in[17];
    const float* fn_b = (const float*)d_in[18];
    const float* n_g  = (const float*)d_in[19];
    const float* n_b  = (const float*)d_in[20];

    const size_t SZ = (size_t)ROWS * DIM;           // 1M elements
    float* X    = (float*)d_ws;                     // fp32 residual stream
    short* Xb   = (short*)(X + SZ);
    short* KVb  = Xb + SZ;
    short* T1b  = KVb + SZ;                         // attn out bf16
    short* Kb4  = T1b + SZ;                         // [L][4096][256] bf16
    short* Vt4  = Kb4 + (size_t)NL * SZ;            // [L][CB][DIM][SKL] bf16
    short* Wqt  = Vt4 + (size_t)NL * SZ;
    short* Wkt  = Wqt + (size_t)NL * DIM * DIM;
    short* Wvt  = Wkt + (size_t)NL * DIM * DIM;
    short* Wot  = Wvt + (size_t)NL * DIM * DIM;
    short* W1t  = Wot + (size_t)NL * DIM * DIM;     // [L][768][256]
    short* W2t  = W1t + (size_t)NL * DIM * FFD;     // [L][256][768]

    {
        int total = CB * SQL * DIM;
        init_kernel<<<(total + 255) / 256, 256, 0, stream>>>(pose, vel, img, X, Xb, KVb);
    }
    transpose_all<<<640, 256, 0, stream>>>(Wq, Wk, Wv, Wo, W1, W2,
                                           Wqt, Wkt, Wvt, Wot, W1t, W2t);
    kv_gemm<<<dim3(DIM / 64, ROWS / 64, 2 * NL), 256, 0, stream>>>(
        KVb, Wkt, Wvt, bk, bv, Kb4, Vt4);

    const float qscale = 0.08838834764831845f;      // 0.5 / sqrt(32)

    for (int i = 0; i < NL; i++) {
        const short* Wqt_i = Wqt + (size_t)i * DIM * DIM;
        const short* Wot_i = Wot + (size_t)i * DIM * DIM;
        const short* W1t_i = W1t + (size_t)i * DIM * FFD;
        const short* W2t_i = W2t + (size_t)i * DIM * FFD;

        attn_mfma<<<2048, 512, 0, stream>>>(
            Xb, Wqt_i, bq + i * DIM, Kb4 + (size_t)i * SZ, Vt4 + (size_t)i * SZ,
            T1b, qscale);

        float* outp  = (i == NL - 1) ? (float*)d_out : X;
        short* outbp = (i == NL - 1) ? nullptr : Xb;
        fused_tail<<<ROWS / 16, 1024, 0, stream>>>(
            T1b, Wot_i, bo + i * DIM, X,
            an_g + i * DIM, an_b + i * DIM, fn_g + i * DIM, fn_b + i * DIM,
            W1t_i, b1 + i * FFD, W2t_i, b2 + i * DIM,
            n_g + i * DIM, n_b + i * DIM, outp, outbp);
    }

    (void)in_sizes; (void)n_in; (void)out_size; (void)ws_size;
}